// Round 1
// baseline (1014.724 us; speedup 1.0000x reference)
//
#include <hip/hip_runtime.h>

#define BATCH 4096
#define MD 384
#define KW 15
#define PADW 7
#define LSEQ 28
#define FIN 28

#define NX (BATCH*LSEQ*FIN)
#define NW1 (MD*FIN)
#define NWC (MD*KW)
#define NWF (10*MD*LSEQ)

// scalar reduction slots (uint-encoded)
#define S_IMG 0
#define S_W1  1
#define S_WC  2
#define S_WF  3
#define S_LINMN 4
#define S_LINMX 5
#define S_CVMN 6
#define S_CVMX 7
#define S_LOG 8

// workspace layout (float offsets)
#define OFF_W1Q 16
#define OFF_WCQ (OFF_W1Q + NW1)
#define OFF_WFQ (OFF_WCQ + NWC)
#define OFF_XQ  (OFF_WFQ + NWF)
#define OFF_LG  (OFF_XQ + NX)
#define OFF_BX  (OFF_LG + BATCH*10)

// ---------- helpers ----------
__device__ __forceinline__ unsigned encf(float f){
  unsigned u=__float_as_uint(f); return (u&0x80000000u)?~u:(u|0x80000000u);
}
__device__ __forceinline__ float decf(unsigned k){
  unsigned u=(k&0x80000000u)?(k^0x80000000u):~k; return __uint_as_float(u);
}

__device__ __forceinline__ float derive_pre_scale(const unsigned* sc,int mnslot,int mxslot){
  float mn=decf(sc[mnslot]), mx=decf(sc[mxslot]);
  float ma=fmaxf(fabsf(mn),fabsf(mx));
  return fmaxf(ma/127.f,1e-8f);
}
// scale of fake_quant(tanh(fake_quant(x,8)),8) given min/max of x
__device__ __forceinline__ float derive_out_scale(const unsigned* sc,int mnslot,int mxslot){
  float mn=decf(sc[mnslot]), mx=decf(sc[mxslot]);
  float ma=fmaxf(fabsf(mn),fabsf(mx));
  float s=fmaxf(ma/127.f,1e-8f);
  float a1=fabsf(fminf(fmaxf(rintf(mn/s),-128.f),127.f)*s);
  float a2=fabsf(fminf(fmaxf(rintf(mx/s),-128.f),127.f)*s);
  return fmaxf(tanhf(fmaxf(a1,a2))/127.f,1e-8f);
}

__device__ __forceinline__ void blockReduceMaxAbs(float m, unsigned* slot){
  #pragma unroll
  for(int off=32;off;off>>=1) m=fmaxf(m,__shfl_xor(m,off,64));
  __shared__ float sm[16];
  int wid=threadIdx.x>>6, lane=threadIdx.x&63;
  int nw=(blockDim.x+63)>>6;
  if(lane==0) sm[wid]=m;
  __syncthreads();
  if(threadIdx.x==0){
    for(int i=1;i<nw;i++) m=fmaxf(m,sm[i]);
    atomicMax(slot,__float_as_uint(m));
  }
  __syncthreads();
}

__device__ __forceinline__ void blockReduceMinMax(float mn,float mx,unsigned* mnslot,unsigned* mxslot){
  #pragma unroll
  for(int off=32;off;off>>=1){
    mn=fminf(mn,__shfl_xor(mn,off,64));
    mx=fmaxf(mx,__shfl_xor(mx,off,64));
  }
  __shared__ float smn[16], smx[16];
  int wid=threadIdx.x>>6, lane=threadIdx.x&63;
  int nw=(blockDim.x+63)>>6;
  if(lane==0){smn[wid]=mn;smx[wid]=mx;}
  __syncthreads();
  if(threadIdx.x==0){
    for(int i=1;i<nw;i++){mn=fminf(mn,smn[i]);mx=fmaxf(mx,smx[i]);}
    atomicMin(mnslot,encf(mn));
    atomicMax(mxslot,encf(mx));
  }
  __syncthreads();
}

// ---------- kernels ----------
__global__ void k_init(unsigned* sc){
  int t=threadIdx.x;
  if(t<16){
    unsigned v=0u;
    if(t==S_LINMN||t==S_CVMN) v=0xFFFFFFFFu;
    sc[t]=v;
  }
}

__global__ __launch_bounds__(256)
void k_maxabs_in(const float* __restrict__ img,const float* __restrict__ W1,
                 const float* __restrict__ Wc,const float* __restrict__ Wf,
                 unsigned* __restrict__ sc){
  float m0=0.f,m1=0.f,m2=0.f,m3=0.f;
  const int total=NX+NW1+NWC+NWF;
  for(int i=blockIdx.x*blockDim.x+threadIdx.x;i<total;i+=gridDim.x*blockDim.x){
    if(i<NX) m0=fmaxf(m0,fabsf(img[i]));
    else if(i<NX+NW1) m1=fmaxf(m1,fabsf(W1[i-NX]));
    else if(i<NX+NW1+NWC) m2=fmaxf(m2,fabsf(Wc[i-NX-NW1]));
    else m3=fmaxf(m3,fabsf(Wf[i-NX-NW1-NWC]));
  }
  blockReduceMaxAbs(m0,&sc[S_IMG]);
  blockReduceMaxAbs(m1,&sc[S_W1]);
  blockReduceMaxAbs(m2,&sc[S_WC]);
  blockReduceMaxAbs(m3,&sc[S_WF]);
}

__global__ __launch_bounds__(256)
void k_prep(const float* __restrict__ img,const float* __restrict__ W1,
            const float* __restrict__ Wc,const float* __restrict__ Wf,
            const unsigned* __restrict__ sc,float* __restrict__ ws){
  float s_img=fmaxf(__uint_as_float(sc[S_IMG])/127.f,1e-8f);
  float s_w1 =fmaxf(__uint_as_float(sc[S_W1])/3.f,1e-8f);
  float s_wc =fmaxf(__uint_as_float(sc[S_WC])/3.f,1e-8f);
  float s_wf =fmaxf(__uint_as_float(sc[S_WF])/3.f,1e-8f);
  float* W1q=ws+OFF_W1Q; float* Wcq=ws+OFF_WCQ; float* Wfq=ws+OFF_WFQ; float* xq=ws+OFF_XQ;
  const int total=NX+NW1+NWC+NWF;
  for(int i=blockIdx.x*blockDim.x+threadIdx.x;i<total;i+=gridDim.x*blockDim.x){
    if(i<NX){
      xq[i]=fminf(fmaxf(rintf(img[i]/s_img),-128.f),127.f)*s_img;
    } else {
      int j=i-NX;
      if(j<NW1){
        W1q[j]=fminf(fmaxf(rintf(W1[j]/s_w1),-4.f),3.f)*s_w1;
      } else if(j<NW1+NWC){
        int k=j-NW1;
        Wcq[k]=fminf(fmaxf(rintf(Wc[k]/s_wc),-4.f),3.f)*s_wc;
      } else {
        int r=j-NW1-NWC;               // dest: o*10752 + c*28 + l
        int o=r/10752; int rr=r-o*10752; int c=rr/LSEQ; int l=rr-c*LSEQ;
        Wfq[r]=fminf(fmaxf(rintf(Wf[o*10752 + l*MD + c]/s_wf),-4.f),3.f)*s_wf;
      }
    }
  }
}

// GEMM1: lin[b,l,o] = sum_f xq[b,l,f]*W1q[o,f] + b1[o]
// WRITE=false: reduce min/max(lin).  WRITE=true: write int8 code of
// fq8(tanh(fq8(lin))) into bxi in [b][o][l] layout (conv input).
template<bool WRITE>
__global__ __launch_bounds__(384)
void k_gemm1(const float* __restrict__ xq,const float* __restrict__ W1q,
             const float* __restrict__ b1,unsigned* __restrict__ sc,
             int* __restrict__ bxi){
  __shared__ float xs[LSEQ*FIN];
  int b=blockIdx.x, t=threadIdx.x;
  const float* xrow=xq+(size_t)b*(LSEQ*FIN);
  for(int i=t;i<LSEQ*FIN;i+=384) xs[i]=xrow[i];
  float w[FIN];
  const float* wr=W1q+t*FIN;
  #pragma unroll
  for(int f=0;f<FIN;f++) w[f]=wr[f];
  float bias=b1[t];
  float s_lin=1.f,s_o1=1.f;
  if constexpr(WRITE){
    s_lin=derive_pre_scale(sc,S_LINMN,S_LINMX);
    s_o1 =derive_out_scale(sc,S_LINMN,S_LINMX);
  }
  __syncthreads();
  float mn=1e30f,mx=-1e30f;
  int qi[LSEQ];
  #pragma unroll
  for(int l=0;l<LSEQ;l++){
    float acc=bias;
    #pragma unroll
    for(int f=0;f<FIN;f++) acc=fmaf(xs[l*FIN+f],w[f],acc);
    if constexpr(WRITE){
      float d=fminf(fmaxf(rintf(acc/s_lin),-128.f),127.f)*s_lin;
      float th=tanhf(d);
      qi[l]=(int)fminf(fmaxf(rintf(th/s_o1),-128.f),127.f);
    } else {
      mn=fminf(mn,acc); mx=fmaxf(mx,acc);
    }
  }
  if constexpr(WRITE){
    __shared__ int olds[MD*7];
    #pragma unroll
    for(int g=0;g<7;g++){
      unsigned wv=((unsigned)(qi[4*g]&0xFF))|((unsigned)(qi[4*g+1]&0xFF)<<8)|
                  ((unsigned)(qi[4*g+2]&0xFF)<<16)|((unsigned)(qi[4*g+3]&0xFF)<<24);
      olds[t*7+g]=(int)wv;
    }
    __syncthreads();
    int* dst=bxi+(size_t)b*(MD*7);
    for(int i=t;i<MD*7;i+=384) dst[i]=olds[i];
  } else {
    blockReduceMinMax(mn,mx,&sc[S_LINMN],&sc[S_LINMX]);
  }
}

// depthwise conv over L=28. thread = one (b,c) row of int8 codes.
// WRITE=false: min/max(conv+bias). WRITE=true: overwrite row in place with
// int8 code of fq8(tanh(fq8(conv+bias))).
template<bool WRITE>
__global__ __launch_bounds__(256)
void k_conv(int* __restrict__ bxi,const float* __restrict__ Wcq,
            const float* __restrict__ bc,unsigned* __restrict__ sc){
  int tid=blockIdx.x*256+threadIdx.x;    // [0, BATCH*MD)
  int c=tid%MD;
  float s_o1=derive_out_scale(sc,S_LINMN,S_LINMX);
  float s_cv=1.f,s_o2=1.f;
  if constexpr(WRITE){
    s_cv=derive_pre_scale(sc,S_CVMN,S_CVMX);
    s_o2=derive_out_scale(sc,S_CVMN,S_CVMX);
  }
  const int* p=bxi+(size_t)tid*7;
  int wbuf[7];
  #pragma unroll
  for(int i=0;i<7;i++) wbuf[i]=p[i];
  float rv[LSEQ];
  #pragma unroll
  for(int j=0;j<LSEQ;j++){
    int wv=wbuf[j>>2];
    rv[j]=(float)((wv<<(24-8*(j&3)))>>24)*s_o1;
  }
  float wc[KW];
  const float* wcp=Wcq+c*KW;
  #pragma unroll
  for(int k=0;k<KW;k++) wc[k]=wcp[k];
  float bias=bc[c];
  float mn=1e30f,mx=-1e30f;
  int qi[LSEQ];
  #pragma unroll
  for(int l=0;l<LSEQ;l++){
    float acc=bias;
    #pragma unroll
    for(int k=0;k<KW;k++){
      int j=l+k-PADW;
      if(j>=0&&j<LSEQ) acc=fmaf(rv[j],wc[k],acc);
    }
    if constexpr(WRITE){
      float d=fminf(fmaxf(rintf(acc/s_cv),-128.f),127.f)*s_cv;
      float th=tanhf(d);
      qi[l]=(int)fminf(fmaxf(rintf(th/s_o2),-128.f),127.f);
    } else {
      mn=fminf(mn,acc); mx=fmaxf(mx,acc);
    }
  }
  if constexpr(WRITE){
    int* dst=bxi+(size_t)tid*7;
    #pragma unroll
    for(int g=0;g<7;g++){
      unsigned wv=((unsigned)(qi[4*g]&0xFF))|((unsigned)(qi[4*g+1]&0xFF)<<8)|
                  ((unsigned)(qi[4*g+2]&0xFF)<<16)|((unsigned)(qi[4*g+3]&0xFF)<<24);
      dst[g]=(int)wv;
    }
  } else {
    blockReduceMinMax(mn,mx,&sc[S_CVMN],&sc[S_CVMX]);
  }
}

// final linear: logits[b,o] = sum_{c,l} deq(bxi[b,c,l]) * Wfq[o, c*28+l] + bf[o]
#define TB 32
#define CH 336
#define CHW 84
#define CHP 337
__global__ __launch_bounds__(320)
void k_gemm2(const int* __restrict__ bxi,const float* __restrict__ Wfq,
             const float* __restrict__ bf,unsigned* __restrict__ sc,
             float* __restrict__ lg){
  __shared__ float Xs[TB][CHP];
  __shared__ float Ws[10][CHP];
  int t=threadIdx.x;
  int b0=blockIdx.x*TB;
  int bs=t&31, og=t>>5;          // 32 rows x 10 outputs = 320 threads
  float s_o2=derive_out_scale(sc,S_CVMN,S_CVMX);
  float acc=bf[og];
  for(int kk=0;kk<32;kk++){
    __syncthreads();
    int kw=kk*CHW;
    for(int i=t;i<TB*CHW;i+=320){
      int r=i/CHW, j=i-r*CHW;
      unsigned wv=(unsigned)bxi[(size_t)(b0+r)*(MD*7)+kw+j];
      float* xp=&Xs[r][j*4];
      xp[0]=(float)((int)(wv<<24)>>24)*s_o2;
      xp[1]=(float)((int)(wv<<16)>>24)*s_o2;
      xp[2]=(float)((int)(wv<<8)>>24)*s_o2;
      xp[3]=(float)((int)wv>>24)*s_o2;
    }
    int kf=kk*CH;
    for(int i=t;i<10*CH;i+=320){
      int r=i/CH, j=i-r*CH;
      Ws[r][j]=Wfq[r*10752+kf+j];
    }
    __syncthreads();
    #pragma unroll 8
    for(int j=0;j<CH;j++) acc=fmaf(Xs[bs][j],Ws[og][j],acc);
  }
  lg[(size_t)(b0+bs)*10+og]=acc;
  blockReduceMaxAbs(fabsf(acc),&sc[S_LOG]);
}

__global__ void k_final(const float* __restrict__ lg,const unsigned* __restrict__ sc,
                        float* __restrict__ out){
  int i=blockIdx.x*256+threadIdx.x;
  if(i<BATCH*10){
    float s=fmaxf(__uint_as_float(sc[S_LOG])/127.f,1e-8f);
    out[i]=fminf(fmaxf(rintf(lg[i]/s),-128.f),127.f)*s;
  }
}

extern "C" void kernel_launch(void* const* d_in, const int* in_sizes, int n_in,
                              void* d_out, int out_size, void* d_ws, size_t ws_size,
                              hipStream_t stream){
  const float* img=(const float*)d_in[0];
  const float* W1 =(const float*)d_in[1];
  const float* b1 =(const float*)d_in[2];
  const float* Wc =(const float*)d_in[3];
  const float* bc =(const float*)d_in[4];
  const float* Wf =(const float*)d_in[5];
  const float* bf =(const float*)d_in[6];
  float* out=(float*)d_out;
  float* ws=(float*)d_ws;
  unsigned* sc=(unsigned*)d_ws;
  int* bxi=(int*)(ws+OFF_BX);
  float* lg=ws+OFF_LG;

  k_init<<<1,64,0,stream>>>(sc);
  k_maxabs_in<<<2048,256,0,stream>>>(img,W1,Wc,Wf,sc);
  k_prep<<<4096,256,0,stream>>>(img,W1,Wc,Wf,sc,ws);
  k_gemm1<false><<<BATCH,384,0,stream>>>(ws+OFF_XQ,ws+OFF_W1Q,b1,sc,bxi);
  k_gemm1<true ><<<BATCH,384,0,stream>>>(ws+OFF_XQ,ws+OFF_W1Q,b1,sc,bxi);
  k_conv<false><<<(BATCH*MD)/256,256,0,stream>>>(bxi,ws+OFF_WCQ,bc,sc);
  k_conv<true ><<<(BATCH*MD)/256,256,0,stream>>>(bxi,ws+OFF_WCQ,bc,sc);
  k_gemm2<<<BATCH/TB,320,0,stream>>>(bxi,ws+OFF_WFQ,bf,sc,lg);
  k_final<<<(BATCH*10+255)/256,256,0,stream>>>(lg,sc,out);
}

// Round 2
// 455.701 us; speedup vs baseline: 2.2267x; 2.2267x over previous
//
#include <hip/hip_runtime.h>

#define BATCH 4096
#define MD 384
#define KW 15
#define PADW 7
#define LSEQ 28
#define FIN 28

#define NX (BATCH*LSEQ*FIN)

// scalar reduction slots (uint-encoded)
#define S_IMG 0
#define S_W1  1
#define S_WC  2
#define S_WF  3
#define S_LINMN 4
#define S_LINMX 5
#define S_CVMN 6
#define S_CVMX 7
#define S_LOG 8

// workspace layout (byte offsets, all 16B-aligned)
#define B_W1B 256
#define B_WCQ 24832
#define B_WFB 47872
#define B_LGI 219904
#define B_LG  482048
#define B_XQB 645888
#define B_BX  7985920

typedef __bf16 bf16x8 __attribute__((ext_vector_type(8)));
typedef float f32x4 __attribute__((ext_vector_type(4)));
typedef int i32x4 __attribute__((ext_vector_type(4)));

// ---------- helpers ----------
__device__ __forceinline__ unsigned encf(float f){
  unsigned u=__float_as_uint(f); return (u&0x80000000u)?~u:(u|0x80000000u);
}
__device__ __forceinline__ float decf(unsigned k){
  unsigned u=(k&0x80000000u)?(k^0x80000000u):~k; return __uint_as_float(u);
}
__device__ __forceinline__ unsigned short f2bf(float f){
  return (unsigned short)(__float_as_uint(f)>>16);   // exact for ints |q|<=256
}

__device__ __forceinline__ float derive_pre_scale(const unsigned* sc,int mnslot,int mxslot){
  float mn=decf(sc[mnslot]), mx=decf(sc[mxslot]);
  float ma=fmaxf(fabsf(mn),fabsf(mx));
  return fmaxf(ma/127.f,1e-8f);
}
__device__ __forceinline__ float derive_out_scale(const unsigned* sc,int mnslot,int mxslot){
  float mn=decf(sc[mnslot]), mx=decf(sc[mxslot]);
  float ma=fmaxf(fabsf(mn),fabsf(mx));
  float s=fmaxf(ma/127.f,1e-8f);
  float a1=fabsf(fminf(fmaxf(rintf(mn/s),-128.f),127.f)*s);
  float a2=fabsf(fminf(fmaxf(rintf(mx/s),-128.f),127.f)*s);
  return fmaxf(tanhf(fmaxf(a1,a2))/127.f,1e-8f);
}

__device__ __forceinline__ void blockReduceMaxAbs(float m, unsigned* slot){
  #pragma unroll
  for(int off=32;off;off>>=1) m=fmaxf(m,__shfl_xor(m,off,64));
  __shared__ float sm[16];
  int wid=threadIdx.x>>6, lane=threadIdx.x&63;
  int nw=(blockDim.x+63)>>6;
  if(lane==0) sm[wid]=m;
  __syncthreads();
  if(threadIdx.x==0){
    for(int i=1;i<nw;i++) m=fmaxf(m,sm[i]);
    atomicMax(slot,__float_as_uint(m));
  }
  __syncthreads();
}

__device__ __forceinline__ void blockReduceMinMax(float mn,float mx,unsigned* mnslot,unsigned* mxslot){
  #pragma unroll
  for(int off=32;off;off>>=1){
    mn=fminf(mn,__shfl_xor(mn,off,64));
    mx=fmaxf(mx,__shfl_xor(mx,off,64));
  }
  __shared__ float smn[16], smx[16];
  int wid=threadIdx.x>>6, lane=threadIdx.x&63;
  int nw=(blockDim.x+63)>>6;
  if(lane==0){smn[wid]=mn;smx[wid]=mx;}
  __syncthreads();
  if(threadIdx.x==0){
    for(int i=1;i<nw;i++){mn=fminf(mn,smn[i]);mx=fmaxf(mx,smx[i]);}
    atomicMin(mnslot,encf(mn));
    atomicMax(mxslot,encf(mx));
  }
  __syncthreads();
}

// ---------- kernels ----------
__global__ void k_init(unsigned* sc,int* lgint){
  int gid=blockIdx.x*256+threadIdx.x;
  if(gid<16){
    unsigned v=0u;
    if(gid==S_LINMN||gid==S_CVMN) v=0xFFFFFFFFu;
    sc[gid]=v;
  }
  if(gid<BATCH*16) lgint[gid]=0;
}

__global__ __launch_bounds__(256)
void k_maxabs_in(const float* __restrict__ img,const float* __restrict__ W1,
                 const float* __restrict__ Wc,const float* __restrict__ Wf,
                 unsigned* __restrict__ sc){
  float m0=0.f,m1=0.f,m2=0.f,m3=0.f;
  const int NW1=MD*FIN, NWC=MD*KW, NWF=10*MD*LSEQ;
  const int total=NX+NW1+NWC+NWF;
  for(int i=blockIdx.x*blockDim.x+threadIdx.x;i<total;i+=gridDim.x*blockDim.x){
    if(i<NX) m0=fmaxf(m0,fabsf(img[i]));
    else if(i<NX+NW1) m1=fmaxf(m1,fabsf(W1[i-NX]));
    else if(i<NX+NW1+NWC) m2=fmaxf(m2,fabsf(Wc[i-NX-NW1]));
    else m3=fmaxf(m3,fabsf(Wf[i-NX-NW1-NWC]));
  }
  blockReduceMaxAbs(m0,&sc[S_IMG]);
  blockReduceMaxAbs(m1,&sc[S_W1]);
  blockReduceMaxAbs(m2,&sc[S_WC]);
  blockReduceMaxAbs(m3,&sc[S_WF]);
}

// quantize everything into code tensors
__global__ __launch_bounds__(256)
void k_prep(const float* __restrict__ img,const float* __restrict__ W1,
            const float* __restrict__ Wc,const float* __restrict__ Wf,
            const unsigned* __restrict__ sc,char* __restrict__ wsb){
  float s_img=fmaxf(__uint_as_float(sc[S_IMG])/127.f,1e-8f);
  float s_w1 =fmaxf(__uint_as_float(sc[S_W1])/3.f,1e-8f);
  float s_wc =fmaxf(__uint_as_float(sc[S_WC])/3.f,1e-8f);
  float s_wf =fmaxf(__uint_as_float(sc[S_WF])/3.f,1e-8f);
  unsigned short* xqb=(unsigned short*)(wsb+B_XQB);
  unsigned short* w1b=(unsigned short*)(wsb+B_W1B);
  float* wcq=(float*)(wsb+B_WCQ);
  char* wfb=wsb+B_WFB;
  const int T0=BATCH*LSEQ*32;          // 3670016 bf16 codes (K padded to 32)
  const int T1=T0+MD*32;               // +12288
  const int T2=T1+MD*KW;               // +5760
  const int T3=T2+168*1024;            // +172032
  for(int i=blockIdx.x*blockDim.x+threadIdx.x;i<T3;i+=gridDim.x*blockDim.x){
    if(i<T0){
      int row=i>>5, cc=i&31;
      float q = cc<FIN ? fminf(fmaxf(rintf(img[row*FIN+cc]/s_img),-128.f),127.f) : 0.f;
      xqb[i]=f2bf(q);
    } else if(i<T1){
      int j=i-T0; int o=j>>5, cc=j&31;
      float q = cc<FIN ? fminf(fmaxf(rintf(W1[o*FIN+cc]/s_w1),-4.f),3.f) : 0.f;
      w1b[j]=f2bf(q);
    } else if(i<T2){
      int j=i-T1;
      wcq[j]=fminf(fmaxf(rintf(Wc[j]/s_wc),-4.f),3.f)*s_wc;
    } else {
      int j=i-T2;
      int s=j>>10, l=(j>>4)&63, jj=j&15;
      int n=l&15, k=s*64+((l>>4)<<4)+jj;
      char q=0;
      if(n<10){
        int c=k/28, ls=k-c*28;
        q=(char)(int)fminf(fmaxf(rintf(Wf[n*10752+ls*MD+c]/s_wf),-4.f),3.f);
      }
      wfb[j]=q;
    }
  }
}

// GEMM1 via bf16 MFMA on integer codes. Block = 4 samples = 112 rows x 384 o.
// WRITE=false: min/max(lin). WRITE=true: write packed int8 codes of
// fq8(tanh(fq8(lin))) into bxi[b][o][l].
template<bool WRITE>
__global__ __launch_bounds__(512)
void k_g1(const unsigned short* __restrict__ xqb,const unsigned short* __restrict__ w1b,
          const float* __restrict__ b1,unsigned* __restrict__ sc,
          int* __restrict__ bxi){
  __shared__ char ldsraw[43456];
  unsigned short* Wlds=(unsigned short*)ldsraw;
  int t=threadIdx.x, wid=t>>6, lane=t&63, l4=lane>>4, l15=lane&15;
  {
    const int* src=(const int*)w1b; int* dst=(int*)ldsraw;
    for(int i=t;i<6144;i+=512) dst[i]=src[i];
  }
  __syncthreads();
  bf16x8 bfr[3]; float b1v[3];
  #pragma unroll
  for(int ni=0;ni<3;ni++){
    int o=(wid*3+ni)*16+l15;
    bfr[ni]=*(const bf16x8*)&Wlds[o*32+l4*8];
    b1v[ni]=b1[o];
  }
  bf16x8 af[7];
  int r0=blockIdx.x*112;
  #pragma unroll
  for(int mt=0;mt<7;mt++)
    af[mt]=*(const bf16x8*)&xqb[(size_t)(r0+mt*16+l15)*32+l4*8];
  float sg=fmaxf(__uint_as_float(sc[S_IMG])/127.f,1e-8f)*
           fmaxf(__uint_as_float(sc[S_W1])/3.f,1e-8f);
  float s_lin=1.f,s_o1=1.f;
  if constexpr(WRITE){
    s_lin=derive_pre_scale(sc,S_LINMN,S_LINMX);
    s_o1 =derive_out_scale(sc,S_LINMN,S_LINMX);
    __syncthreads();     // all waves done reading Wlds before reuse as Xt
  }
  char* Xt=ldsraw;
  float mn=1e30f,mx=-1e30f;
  f32x4 zero={0.f,0.f,0.f,0.f};
  #pragma unroll
  for(int ni=0;ni<3;ni++){
    #pragma unroll
    for(int mt=0;mt<7;mt++){
      f32x4 acc=__builtin_amdgcn_mfma_f32_16x16x32_bf16(af[mt],bfr[ni],zero,0,0,0);
      #pragma unroll
      for(int r=0;r<4;r++){
        float v=sg*acc[r]+b1v[ni];
        if constexpr(WRITE){
          float d=fminf(fmaxf(rintf(v/s_lin),-128.f),127.f)*s_lin;
          int q=(int)fminf(fmaxf(rintf(tanhf(d)/s_o1),-128.f),127.f);
          int row=mt*16+l4*4+r;
          int o=(wid*3+ni)*16+l15;
          Xt[row*388+o]=(char)q;
        } else {
          mn=fminf(mn,v); mx=fmaxf(mx,v);
        }
      }
    }
  }
  if constexpr(WRITE){
    __syncthreads();
    int b0=blockIdx.x*4;
    for(int i=t;i<10752;i+=512){
      int bl=i/2688, rem=i-bl*2688;
      int o=rem/7, g=rem-o*7;
      int base=(bl*28+g*4)*388+o;
      unsigned w=(unsigned)(unsigned char)Xt[base]
               |((unsigned)(unsigned char)Xt[base+388])<<8
               |((unsigned)(unsigned char)Xt[base+776])<<16
               |((unsigned)(unsigned char)Xt[base+1164])<<24;
      bxi[(size_t)(b0+bl)*2688+o*7+g]=(int)w;
    }
  } else {
    blockReduceMinMax(mn,mx,&sc[S_LINMN],&sc[S_LINMX]);
  }
}

// depthwise conv over L=28. thread = one (b,c) row of int8 codes.
template<bool WRITE>
__global__ __launch_bounds__(256)
void k_conv(int* __restrict__ bxi,const float* __restrict__ Wcq,
            const float* __restrict__ bc,unsigned* __restrict__ sc){
  int tid=blockIdx.x*256+threadIdx.x;    // [0, BATCH*MD)
  int c=tid%MD;
  float s_o1=derive_out_scale(sc,S_LINMN,S_LINMX);
  float s_cv=1.f,s_o2=1.f;
  if constexpr(WRITE){
    s_cv=derive_pre_scale(sc,S_CVMN,S_CVMX);
    s_o2=derive_out_scale(sc,S_CVMN,S_CVMX);
  }
  const int* p=bxi+(size_t)tid*7;
  int wbuf[7];
  #pragma unroll
  for(int i=0;i<7;i++) wbuf[i]=p[i];
  float rv[LSEQ];
  #pragma unroll
  for(int j=0;j<LSEQ;j++){
    int wv=wbuf[j>>2];
    rv[j]=(float)((wv<<(24-8*(j&3)))>>24)*s_o1;
  }
  float wc[KW];
  const float* wcp=Wcq+c*KW;
  #pragma unroll
  for(int k=0;k<KW;k++) wc[k]=wcp[k];
  float bias=bc[c];
  float mn=1e30f,mx=-1e30f;
  int qi[LSEQ];
  #pragma unroll
  for(int l=0;l<LSEQ;l++){
    float acc=bias;
    #pragma unroll
    for(int k=0;k<KW;k++){
      int j=l+k-PADW;
      if(j>=0&&j<LSEQ) acc=fmaf(rv[j],wc[k],acc);
    }
    if constexpr(WRITE){
      float d=fminf(fmaxf(rintf(acc/s_cv),-128.f),127.f)*s_cv;
      float th=tanhf(d);
      qi[l]=(int)fminf(fmaxf(rintf(th/s_o2),-128.f),127.f);
    } else {
      mn=fminf(mn,acc); mx=fmaxf(mx,acc);
    }
  }
  if constexpr(WRITE){
    int* dst=bxi+(size_t)tid*7;
    #pragma unroll
    for(int g=0;g<7;g++){
      unsigned wv=((unsigned)(qi[4*g]&0xFF))|((unsigned)(qi[4*g+1]&0xFF)<<8)|
                  ((unsigned)(qi[4*g+2]&0xFF)<<16)|((unsigned)(qi[4*g+3]&0xFF)<<24);
      dst[g]=(int)wv;
    }
  } else {
    blockReduceMinMax(mn,mx,&sc[S_CVMN],&sc[S_CVMX]);
  }
}

// final linear via i8 MFMA: exact int32 dot. 256 m-tiles x 8 K-parts, 1 wave each.
__global__ __launch_bounds__(64)
void k_gemm2(const char* __restrict__ bxb,const char* __restrict__ wfb,
             int* __restrict__ lgint){
  int mt=blockIdx.x>>3, kp=blockIdx.x&7;
  int lane=threadIdx.x, l4=lane>>4, l15=lane&15;
  const char* ap=bxb+(size_t)(mt*16+l15)*10752+l4*16;
  const char* bp=wfb+lane*16;
  i32x4 acc={0,0,0,0};
  int s0=kp*21;
  #pragma unroll 3
  for(int s=s0;s<s0+21;++s){
    i32x4 a=*(const i32x4*)(ap+(size_t)s*64);
    i32x4 b=*(const i32x4*)(bp+(size_t)s*1024);
    acc=__builtin_amdgcn_mfma_i32_16x16x64_i8(a,b,acc,0,0,0);
  }
  int rbase=mt*16+l4*4;
  #pragma unroll
  for(int r=0;r<4;r++) atomicAdd(&lgint[(rbase+r)*16+l15],acc[r]);
}

__global__ __launch_bounds__(256)
void k_logmax(const int* __restrict__ lgint,const float* __restrict__ bfv,
              unsigned* __restrict__ sc,float* __restrict__ lg){
  int i=blockIdx.x*256+threadIdx.x;
  float s_wf=fmaxf(__uint_as_float(sc[S_WF])/3.f,1e-8f);
  float s_o2=derive_out_scale(sc,S_CVMN,S_CVMX);
  float s=s_wf*s_o2;
  float m=0.f;
  if(i<BATCH*10){
    int b=i/10, o=i-b*10;
    float v=s*(float)lgint[b*16+o]+bfv[o];
    lg[i]=v; m=fabsf(v);
  }
  blockReduceMaxAbs(m,&sc[S_LOG]);
}

__global__ void k_final(const float* __restrict__ lg,const unsigned* __restrict__ sc,
                        float* __restrict__ out){
  int i=blockIdx.x*256+threadIdx.x;
  if(i<BATCH*10){
    float s=fmaxf(__uint_as_float(sc[S_LOG])/127.f,1e-8f);
    out[i]=fminf(fmaxf(rintf(lg[i]/s),-128.f),127.f)*s;
  }
}

extern "C" void kernel_launch(void* const* d_in, const int* in_sizes, int n_in,
                              void* d_out, int out_size, void* d_ws, size_t ws_size,
                              hipStream_t stream){
  const float* img=(const float*)d_in[0];
  const float* W1 =(const float*)d_in[1];
  const float* b1 =(const float*)d_in[2];
  const float* Wc =(const float*)d_in[3];
  const float* bc =(const float*)d_in[4];
  const float* Wf =(const float*)d_in[5];
  const float* bf =(const float*)d_in[6];
  float* out=(float*)d_out;
  char* wsb=(char*)d_ws;
  unsigned* sc=(unsigned*)wsb;
  int* lgint=(int*)(wsb+B_LGI);
  float* lg=(float*)(wsb+B_LG);
  int* bxi=(int*)(wsb+B_BX);

  k_init<<<256,256,0,stream>>>(sc,lgint);
  k_maxabs_in<<<2048,256,0,stream>>>(img,W1,Wc,Wf,sc);
  k_prep<<<4096,256,0,stream>>>(img,W1,Wc,Wf,sc,wsb);
  k_g1<false><<<1024,512,0,stream>>>((const unsigned short*)(wsb+B_XQB),
                                     (const unsigned short*)(wsb+B_W1B),b1,sc,bxi);
  k_g1<true ><<<1024,512,0,stream>>>((const unsigned short*)(wsb+B_XQB),
                                     (const unsigned short*)(wsb+B_W1B),b1,sc,bxi);
  k_conv<false><<<(BATCH*MD)/256,256,0,stream>>>(bxi,(const float*)(wsb+B_WCQ),bc,sc);
  k_conv<true ><<<(BATCH*MD)/256,256,0,stream>>>(bxi,(const float*)(wsb+B_WCQ),bc,sc);
  k_gemm2<<<2048,64,0,stream>>>((const char*)bxi,wsb+B_WFB,lgint);
  k_logmax<<<160,256,0,stream>>>(lgint,bf,sc,lg);
  k_final<<<160,256,0,stream>>>(lg,sc,out);
}

// Round 3
// 356.892 us; speedup vs baseline: 2.8432x; 1.2769x over previous
//
#include <hip/hip_runtime.h>

#define BATCH 4096
#define MD 384
#define KW 15
#define PADW 7
#define LSEQ 28
#define FIN 28

#define NX (BATCH*LSEQ*FIN)

// scalar reduction slots (uint-encoded)
#define S_IMG 0
#define S_W1  1
#define S_WC  2
#define S_WF  3
#define S_LINMN 4
#define S_LINMX 5
#define S_CVMN 6
#define S_CVMX 7
#define S_LOG 8

// workspace layout (byte offsets, all 16B-aligned)
#define B_W1B 256
#define B_WCQ 24832
#define B_WFB 47872
#define B_LGI 219904
#define B_LG  482048
#define B_XQB 645888
#define B_BX  7985920

typedef __bf16 bf16x8 __attribute__((ext_vector_type(8)));
typedef float f32x4 __attribute__((ext_vector_type(4)));
typedef int i32x4 __attribute__((ext_vector_type(4)));

#if __has_builtin(__builtin_amdgcn_sdot4)
#define SDOT4(a,b,c) __builtin_amdgcn_sdot4((a),(b),(c),false)
#else
__device__ __forceinline__ int SDOT4(int a,int b,int c){
  c += ((a<<24)>>24)*((b<<24)>>24);
  c += ((a<<16)>>24)*((b<<16)>>24);
  c += ((a<<8)>>24)*((b<<8)>>24);
  c += (a>>24)*(b>>24);
  return c;
}
#endif

#if __has_builtin(__builtin_amdgcn_alignbyte)
#define ALIGNB(hi,lo,s) __builtin_amdgcn_alignbyte((hi),(lo),(s))
#else
#define ALIGNB(hi,lo,s) ((int)(((unsigned)(lo)>>(8*(s)))|((unsigned)(hi)<<(32-8*(s)))))
#endif

// ---------- helpers ----------
__device__ __forceinline__ unsigned encf(float f){
  unsigned u=__float_as_uint(f); return (u&0x80000000u)?~u:(u|0x80000000u);
}
__device__ __forceinline__ float decf(unsigned k){
  unsigned u=(k&0x80000000u)?(k^0x80000000u):~k; return __uint_as_float(u);
}
__device__ __forceinline__ unsigned short f2bf(float f){
  return (unsigned short)(__float_as_uint(f)>>16);   // exact for ints |q|<=256
}

__device__ __forceinline__ float derive_pre_scale(const unsigned* sc,int mnslot,int mxslot){
  float mn=decf(sc[mnslot]), mx=decf(sc[mxslot]);
  float ma=fmaxf(fabsf(mn),fabsf(mx));
  return fmaxf(ma/127.f,1e-8f);
}
__device__ __forceinline__ float derive_out_scale(const unsigned* sc,int mnslot,int mxslot){
  float mn=decf(sc[mnslot]), mx=decf(sc[mxslot]);
  float ma=fmaxf(fabsf(mn),fabsf(mx));
  float s=fmaxf(ma/127.f,1e-8f);
  float a1=fabsf(fminf(fmaxf(rintf(mn/s),-128.f),127.f)*s);
  float a2=fabsf(fminf(fmaxf(rintf(mx/s),-128.f),127.f)*s);
  return fmaxf(tanhf(fmaxf(a1,a2))/127.f,1e-8f);
}

__device__ __forceinline__ void blockReduceMaxAbs(float m, unsigned* slot){
  #pragma unroll
  for(int off=32;off;off>>=1) m=fmaxf(m,__shfl_xor(m,off,64));
  __shared__ float sm[16];
  int wid=threadIdx.x>>6, lane=threadIdx.x&63;
  int nw=(blockDim.x+63)>>6;
  if(lane==0) sm[wid]=m;
  __syncthreads();
  if(threadIdx.x==0){
    for(int i=1;i<nw;i++) m=fmaxf(m,sm[i]);
    atomicMax(slot,__float_as_uint(m));
  }
  __syncthreads();
}

__device__ __forceinline__ void blockReduceMinMax(float mn,float mx,unsigned* mnslot,unsigned* mxslot){
  #pragma unroll
  for(int off=32;off;off>>=1){
    mn=fminf(mn,__shfl_xor(mn,off,64));
    mx=fmaxf(mx,__shfl_xor(mx,off,64));
  }
  __shared__ float smn[16], smx[16];
  int wid=threadIdx.x>>6, lane=threadIdx.x&63;
  int nw=(blockDim.x+63)>>6;
  if(lane==0){smn[wid]=mn;smx[wid]=mx;}
  __syncthreads();
  if(threadIdx.x==0){
    for(int i=1;i<nw;i++){mn=fminf(mn,smn[i]);mx=fmaxf(mx,smx[i]);}
    atomicMin(mnslot,encf(mn));
    atomicMax(mxslot,encf(mx));
  }
  __syncthreads();
}

// ---------- kernels ----------
__global__ void k_init(unsigned* sc,int* lgint){
  int gid=blockIdx.x*256+threadIdx.x;
  if(gid<16){
    unsigned v=0u;
    if(gid==S_LINMN||gid==S_CVMN) v=0xFFFFFFFFu;
    sc[gid]=v;
  }
  if(gid<BATCH*16) lgint[gid]=0;
}

__global__ __launch_bounds__(256)
void k_maxabs_in(const float* __restrict__ img,const float* __restrict__ W1,
                 const float* __restrict__ Wc,const float* __restrict__ Wf,
                 unsigned* __restrict__ sc){
  float m0=0.f,m1=0.f,m2=0.f,m3=0.f;
  const int N4=NX/4;
  const int NW1=MD*FIN, NWC=MD*KW, NWF=10*MD*LSEQ;
  const int total=N4+NW1+NWC+NWF;
  const float4* img4=(const float4*)img;
  for(int i=blockIdx.x*blockDim.x+threadIdx.x;i<total;i+=gridDim.x*blockDim.x){
    if(i<N4){
      float4 v=img4[i];
      m0=fmaxf(m0,fmaxf(fmaxf(fabsf(v.x),fabsf(v.y)),fmaxf(fabsf(v.z),fabsf(v.w))));
    }
    else if(i<N4+NW1) m1=fmaxf(m1,fabsf(W1[i-N4]));
    else if(i<N4+NW1+NWC) m2=fmaxf(m2,fabsf(Wc[i-N4-NW1]));
    else m3=fmaxf(m3,fabsf(Wf[i-N4-NW1-NWC]));
  }
  blockReduceMaxAbs(m0,&sc[S_IMG]);
  blockReduceMaxAbs(m1,&sc[S_W1]);
  blockReduceMaxAbs(m2,&sc[S_WC]);
  blockReduceMaxAbs(m3,&sc[S_WF]);
}

// quantize everything into code tensors
__global__ __launch_bounds__(256)
void k_prep(const float* __restrict__ img,const float* __restrict__ W1,
            const float* __restrict__ Wc,const float* __restrict__ Wf,
            const unsigned* __restrict__ sc,char* __restrict__ wsb){
  float s_img=fmaxf(__uint_as_float(sc[S_IMG])/127.f,1e-8f);
  float s_w1 =fmaxf(__uint_as_float(sc[S_W1])/3.f,1e-8f);
  float s_wc =fmaxf(__uint_as_float(sc[S_WC])/3.f,1e-8f);
  float s_wf =fmaxf(__uint_as_float(sc[S_WF])/3.f,1e-8f);
  float inv_img=1.f/s_img;
  unsigned short* xqb=(unsigned short*)(wsb+B_XQB);
  unsigned short* w1b=(unsigned short*)(wsb+B_W1B);
  char* wcpk=wsb+B_WCQ;
  char* wfb=wsb+B_WFB;
  const int T0=BATCH*LSEQ*32;          // bf16 codes (K padded to 32)
  const int T1=T0+MD*32;
  const int T2=T1+MD*16;               // packed i8 conv weights (15 taps + 0 pad)
  const int T3=T2+168*1024;
  for(int i=blockIdx.x*blockDim.x+threadIdx.x;i<T3;i+=gridDim.x*blockDim.x){
    if(i<T0){
      int row=i>>5, cc=i&31;
      float q = cc<FIN ? fminf(fmaxf(rintf(img[row*FIN+cc]*inv_img),-128.f),127.f) : 0.f;
      xqb[i]=f2bf(q);
    } else if(i<T1){
      int j=i-T0; int o=j>>5, cc=j&31;
      float q = cc<FIN ? fminf(fmaxf(rintf(W1[o*FIN+cc]/s_w1),-4.f),3.f) : 0.f;
      w1b[j]=f2bf(q);
    } else if(i<T2){
      int j=i-T1; int c=j>>4, k=j&15;
      char q=0;
      if(k<KW) q=(char)(int)fminf(fmaxf(rintf(Wc[c*KW+k]/s_wc),-4.f),3.f);
      wcpk[j]=q;
    } else {
      int j=i-T2;
      int s=j>>10, l=(j>>4)&63, jj=j&15;
      int n=l&15, k=s*64+((l>>4)<<4)+jj;
      char q=0;
      if(n<10){
        int c=k/28, ls=k-c*28;
        q=(char)(int)fminf(fmaxf(rintf(Wf[n*10752+ls*MD+c]/s_wf),-4.f),3.f);
      }
      wfb[j]=q;
    }
  }
}

// GEMM1 via bf16 MFMA on integer codes. Block = 4 samples = 112 rows x 384 o.
template<bool WRITE>
__global__ __launch_bounds__(512)
void k_g1(const unsigned short* __restrict__ xqb,const unsigned short* __restrict__ w1b,
          const float* __restrict__ b1,unsigned* __restrict__ sc,
          int* __restrict__ bxi){
  __shared__ char ldsraw[43456];
  __shared__ char lut1[256];
  unsigned short* Wlds=(unsigned short*)ldsraw;
  int t=threadIdx.x, wid=t>>6, lane=t&63, l4=lane>>4, l15=lane&15;
  {
    const int* src=(const int*)w1b; int* dst=(int*)ldsraw;
    for(int i=t;i<6144;i+=512) dst[i]=src[i];
  }
  __syncthreads();
  bf16x8 bfr[3]; float b1v[3];
  #pragma unroll
  for(int ni=0;ni<3;ni++){
    int o=(wid*3+ni)*16+l15;
    bfr[ni]=*(const bf16x8*)&Wlds[o*32+l4*8];
    b1v[ni]=b1[o];
  }
  bf16x8 af[7];
  int r0=blockIdx.x*112;
  #pragma unroll
  for(int mt=0;mt<7;mt++)
    af[mt]=*(const bf16x8*)&xqb[(size_t)(r0+mt*16+l15)*32+l4*8];
  float sg=fmaxf(__uint_as_float(sc[S_IMG])/127.f,1e-8f)*
           fmaxf(__uint_as_float(sc[S_W1])/3.f,1e-8f);
  float inv_lin=1.f;
  if constexpr(WRITE){
    float s_lin=derive_pre_scale(sc,S_LINMN,S_LINMX);
    float s_o1 =derive_out_scale(sc,S_LINMN,S_LINMX);
    inv_lin=1.f/s_lin;
    if(t<256){
      float d=(float)(t-128)*s_lin;
      lut1[t]=(char)(int)fminf(fmaxf(rintf(tanhf(d)/s_o1),-128.f),127.f);
    }
    __syncthreads();     // Wlds reads done + lut1 visible before reuse as Xt
  }
  char* Xt=ldsraw;
  float mn=1e30f,mx=-1e30f;
  f32x4 zero={0.f,0.f,0.f,0.f};
  #pragma unroll
  for(int ni=0;ni<3;ni++){
    #pragma unroll
    for(int mt=0;mt<7;mt++){
      f32x4 acc=__builtin_amdgcn_mfma_f32_16x16x32_bf16(af[mt],bfr[ni],zero,0,0,0);
      #pragma unroll
      for(int r=0;r<4;r++){
        float v=sg*acc[r]+b1v[ni];
        if constexpr(WRITE){
          int ql=(int)fminf(fmaxf(rintf(v*inv_lin),-128.f),127.f);
          int q=(int)lut1[ql+128];
          int row=mt*16+l4*4+r;
          int o=(wid*3+ni)*16+l15;
          Xt[row*388+o]=(char)q;
        } else {
          mn=fminf(mn,v); mx=fmaxf(mx,v);
        }
      }
    }
  }
  if constexpr(WRITE){
    __syncthreads();
    int b0=blockIdx.x*4;
    for(int i=t;i<10752;i+=512){
      int bl=i/2688, rem=i-bl*2688;
      int o=rem/7, g=rem-o*7;
      int base=(bl*28+g*4)*388+o;
      unsigned w=(unsigned)(unsigned char)Xt[base]
               |((unsigned)(unsigned char)Xt[base+388])<<8
               |((unsigned)(unsigned char)Xt[base+776])<<16
               |((unsigned)(unsigned char)Xt[base+1164])<<24;
      bxi[(size_t)(b0+bl)*2688+o*7+g]=(int)w;
    }
  } else {
    blockReduceMinMax(mn,mx,&sc[S_LINMN],&sc[S_LINMX]);
  }
}

// depthwise conv, integer dot path. thread = one (b,c) row of packed int8 codes.
// Window built with alignbyte from zero-padded extended words; dot via sdot4.
template<bool WRITE>
__global__ __launch_bounds__(256)
void k_conv(int* __restrict__ bxi,const char* __restrict__ wcpk,
            const float* __restrict__ bc,unsigned* __restrict__ sc){
  __shared__ int rows[1792];
  __shared__ char lut[256];
  int t=threadIdx.x;
  int tid0=blockIdx.x*256;
  int base=tid0*7;
  #pragma unroll
  for(int i=0;i<7;i++) rows[i*256+t]=bxi[base+i*256+t];

  float s_wc=fmaxf(__uint_as_float(sc[S_WC])/3.f,1e-8f);
  float s_o1=derive_out_scale(sc,S_LINMN,S_LINMX);
  float sfac=s_o1*s_wc;                   // deq scale for integer conv dot
  float inv_cv=1.f;
  if constexpr(WRITE){
    float s_cv=derive_pre_scale(sc,S_CVMN,S_CVMX);
    float s_o2=derive_out_scale(sc,S_CVMN,S_CVMX);
    inv_cv=1.f/s_cv;
    float d=(float)(t-128)*s_cv;
    lut[t]=(char)(int)fminf(fmaxf(rintf(tanhf(d)/s_o2),-128.f),127.f);
  }
  __syncthreads();

  int c=(tid0+t)%MD;
  i32x4 wq=*(const i32x4*)(wcpk+(size_t)c*16);
  float bias=bc[c];
  int ext[11];
  ext[0]=0; ext[1]=0; ext[9]=0; ext[10]=0;
  #pragma unroll
  for(int j=0;j<7;j++) ext[2+j]=rows[t*7+j];

  float mn=1e30f,mx=-1e30f;
  unsigned ow[7];
  #pragma unroll
  for(int l=0;l<LSEQ;l++){
    const int eb=l+1, bi=eb>>2, s=eb&3;
    int A0,A1,A2,A3;
    if(s==0){A0=ext[bi];A1=ext[bi+1];A2=ext[bi+2];A3=ext[bi+3];}
    else{
      A0=ALIGNB(ext[bi+1],ext[bi],s);
      A1=ALIGNB(ext[bi+2],ext[bi+1],s);
      A2=ALIGNB(ext[bi+3],ext[bi+2],s);
      A3=ALIGNB(ext[bi+4],ext[bi+3],s);
    }
    int idot=SDOT4(A0,wq[0],SDOT4(A1,wq[1],SDOT4(A2,wq[2],SDOT4(A3,wq[3],0))));
    float v=fmaf((float)idot,sfac,bias);
    if constexpr(WRITE){
      int qc=(int)fminf(fmaxf(rintf(v*inv_cv),-128.f),127.f);
      unsigned q2=(unsigned)(unsigned char)lut[qc+128];
      if((l&3)==0) ow[l>>2]=q2;
      else ow[l>>2]|=q2<<(8*(l&3));
    } else {
      mn=fminf(mn,v); mx=fmaxf(mx,v);
    }
  }
  if constexpr(WRITE){
    #pragma unroll
    for(int j=0;j<7;j++) rows[t*7+j]=(int)ow[j];
    __syncthreads();
    #pragma unroll
    for(int i=0;i<7;i++) bxi[base+i*256+t]=rows[i*256+t];
  } else {
    blockReduceMinMax(mn,mx,&sc[S_CVMN],&sc[S_CVMX]);
  }
}

// final linear via i8 MFMA: exact int32 dot. 256 m-tiles x 8 K-parts, 1 wave each.
__global__ __launch_bounds__(64)
void k_gemm2(const char* __restrict__ bxb,const char* __restrict__ wfb,
             int* __restrict__ lgint){
  int mt=blockIdx.x>>3, kp=blockIdx.x&7;
  int lane=threadIdx.x, l4=lane>>4, l15=lane&15;
  const char* ap=bxb+(size_t)(mt*16+l15)*10752+l4*16;
  const char* bp=wfb+lane*16;
  i32x4 acc={0,0,0,0};
  int s0=kp*21;
  #pragma unroll 3
  for(int s=s0;s<s0+21;++s){
    i32x4 a=*(const i32x4*)(ap+(size_t)s*64);
    i32x4 b=*(const i32x4*)(bp+(size_t)s*1024);
    acc=__builtin_amdgcn_mfma_i32_16x16x64_i8(a,b,acc,0,0,0);
  }
  int rbase=mt*16+l4*4;
  #pragma unroll
  for(int r=0;r<4;r++) atomicAdd(&lgint[(rbase+r)*16+l15],acc[r]);
}

__global__ __launch_bounds__(256)
void k_logmax(const int* __restrict__ lgint,const float* __restrict__ bfv,
              unsigned* __restrict__ sc,float* __restrict__ lg){
  int i=blockIdx.x*256+threadIdx.x;
  float s_wf=fmaxf(__uint_as_float(sc[S_WF])/3.f,1e-8f);
  float s_o2=derive_out_scale(sc,S_CVMN,S_CVMX);
  float s=s_wf*s_o2;
  float m=0.f;
  if(i<BATCH*10){
    int b=i/10, o=i-b*10;
    float v=s*(float)lgint[b*16+o]+bfv[o];
    lg[i]=v; m=fabsf(v);
  }
  blockReduceMaxAbs(m,&sc[S_LOG]);
}

__global__ void k_final(const float* __restrict__ lg,const unsigned* __restrict__ sc,
                        float* __restrict__ out){
  int i=blockIdx.x*256+threadIdx.x;
  if(i<BATCH*10){
    float s=fmaxf(__uint_as_float(sc[S_LOG])/127.f,1e-8f);
    out[i]=fminf(fmaxf(rintf(lg[i]/s),-128.f),127.f)*s;
  }
}

extern "C" void kernel_launch(void* const* d_in, const int* in_sizes, int n_in,
                              void* d_out, int out_size, void* d_ws, size_t ws_size,
                              hipStream_t stream){
  const float* img=(const float*)d_in[0];
  const float* W1 =(const float*)d_in[1];
  const float* b1 =(const float*)d_in[2];
  const float* Wc =(const float*)d_in[3];
  const float* bc =(const float*)d_in[4];
  const float* Wf =(const float*)d_in[5];
  const float* bf =(const float*)d_in[6];
  float* out=(float*)d_out;
  char* wsb=(char*)d_ws;
  unsigned* sc=(unsigned*)wsb;
  int* lgint=(int*)(wsb+B_LGI);
  float* lg=(float*)(wsb+B_LG);
  int* bxi=(int*)(wsb+B_BX);

  k_init<<<256,256,0,stream>>>(sc,lgint);
  k_maxabs_in<<<2048,256,0,stream>>>(img,W1,Wc,Wf,sc);
  k_prep<<<4096,256,0,stream>>>(img,W1,Wc,Wf,sc,wsb);
  k_g1<false><<<1024,512,0,stream>>>((const unsigned short*)(wsb+B_XQB),
                                     (const unsigned short*)(wsb+B_W1B),b1,sc,bxi);
  k_g1<true ><<<1024,512,0,stream>>>((const unsigned short*)(wsb+B_XQB),
                                     (const unsigned short*)(wsb+B_W1B),b1,sc,bxi);
  k_conv<false><<<(BATCH*MD)/256,256,0,stream>>>(bxi,wsb+B_WCQ,bc,sc);
  k_conv<true ><<<(BATCH*MD)/256,256,0,stream>>>(bxi,wsb+B_WCQ,bc,sc);
  k_gemm2<<<2048,64,0,stream>>>((const char*)bxi,wsb+B_WFB,lgint);
  k_logmax<<<160,256,0,stream>>>(lgint,bf,sc,lg);
  k_final<<<160,256,0,stream>>>(lg,sc,out);
}

// Round 4
// 118.261 us; speedup vs baseline: 8.5803x; 3.0178x over previous
//
#include <hip/hip_runtime.h>

#define BATCH 4096
#define MD 384
#define KW 15
#define PADW 7
#define LSEQ 28
#define FIN 28

#define NX (BATCH*LSEQ*FIN)

// scf slots (plain floats, written by reduce kernels)
// 0 s_img, 1 s_w1, 2 s_wc, 3 s_wf, 4 s_lin, 5 s_o1, 6 s_cv, 7 s_o2

// workspace layout (byte offsets, 16B-aligned)
#define B_SCF  0
#define B_LUT1 256
#define B_LUT2 512
#define B_PT0  4096      // 2048 float4
#define B_PT1  36864     // 1024 float2
#define B_PT2  45056     // 6144 float2
#define B_PTL  94208     // 160 float
#define B_W1B  95232     // MD*32 bf16 = 24576
#define B_WCQ  119808    // MD*16 i8   = 6144
#define B_WFB  125952    // 168*1024 i8 = 172032
#define B_LGI  298240    // 4 slices * 4096*16 int = 1048576
#define B_LG   1346816   // 40960 float
#define B_XQB  1510656   // BATCH*28*32 bf16 = 7340032
#define B_BX   8850688   // BATCH*MD*7 int = 44040192

typedef __bf16 bf16x8 __attribute__((ext_vector_type(8)));
typedef float f32x4 __attribute__((ext_vector_type(4)));
typedef int i32x4 __attribute__((ext_vector_type(4)));

#if __has_builtin(__builtin_amdgcn_sdot4)
#define SDOT4(a,b,c) __builtin_amdgcn_sdot4((a),(b),(c),false)
#else
__device__ __forceinline__ int SDOT4(int a,int b,int c){
  c += ((a<<24)>>24)*((b<<24)>>24);
  c += ((a<<16)>>24)*((b<<16)>>24);
  c += ((a<<8)>>24)*((b<<8)>>24);
  c += (a>>24)*(b>>24);
  return c;
}
#endif

#if __has_builtin(__builtin_amdgcn_alignbyte)
#define ALIGNB(hi,lo,s) __builtin_amdgcn_alignbyte((hi),(lo),(s))
#else
#define ALIGNB(hi,lo,s) ((int)(((unsigned)(lo)>>(8*(s)))|((unsigned)(hi)<<(32-8*(s)))))
#endif

__device__ __forceinline__ unsigned short f2bf(float f){
  return (unsigned short)(__float_as_uint(f)>>16);   // exact for small ints
}

// block-reduce 4 maxes, thread0 stores float4 partial (blockDim=256)
__device__ __forceinline__ void blkStore4(float m0,float m1,float m2,float m3,float4* dst){
  #pragma unroll
  for(int off=32;off;off>>=1){
    m0=fmaxf(m0,__shfl_xor(m0,off,64));
    m1=fmaxf(m1,__shfl_xor(m1,off,64));
    m2=fmaxf(m2,__shfl_xor(m2,off,64));
    m3=fmaxf(m3,__shfl_xor(m3,off,64));
  }
  __shared__ float sm[4][4];
  int wid=threadIdx.x>>6;
  if((threadIdx.x&63)==0){sm[wid][0]=m0;sm[wid][1]=m1;sm[wid][2]=m2;sm[wid][3]=m3;}
  __syncthreads();
  if(threadIdx.x==0){
    for(int i=1;i<4;i++){
      m0=fmaxf(m0,sm[i][0]);m1=fmaxf(m1,sm[i][1]);
      m2=fmaxf(m2,sm[i][2]);m3=fmaxf(m3,sm[i][3]);
    }
    *dst=make_float4(m0,m1,m2,m3);
  }
}

// block-reduce min/max, thread0 stores float2 partial
__device__ __forceinline__ void blkStoreMM(float mn,float mx,float2* dst){
  #pragma unroll
  for(int off=32;off;off>>=1){
    mn=fminf(mn,__shfl_xor(mn,off,64));
    mx=fmaxf(mx,__shfl_xor(mx,off,64));
  }
  __shared__ float smn[8],smx[8];
  int wid=threadIdx.x>>6, nw=blockDim.x>>6;
  if((threadIdx.x&63)==0){smn[wid]=mn;smx[wid]=mx;}
  __syncthreads();
  if(threadIdx.x==0){
    for(int i=1;i<nw;i++){mn=fminf(mn,smn[i]);mx=fmaxf(mx,smx[i]);}
    *dst=make_float2(mn,mx);
  }
}

// ---------- kernels ----------
__global__ __launch_bounds__(256)
void k_maxabs_in(const float* __restrict__ img,const float* __restrict__ W1,
                 const float* __restrict__ Wc,const float* __restrict__ Wf,
                 float4* __restrict__ pt0){
  float m0=0.f,m1=0.f,m2=0.f,m3=0.f;
  const int N4=NX/4;
  const int NW1=MD*FIN, NWC=MD*KW, NWF=10*MD*LSEQ;
  const int total=N4+NW1+NWC+NWF;
  const float4* img4=(const float4*)img;
  for(int i=blockIdx.x*blockDim.x+threadIdx.x;i<total;i+=gridDim.x*blockDim.x){
    if(i<N4){
      float4 v=img4[i];
      m0=fmaxf(m0,fmaxf(fmaxf(fabsf(v.x),fabsf(v.y)),fmaxf(fabsf(v.z),fabsf(v.w))));
    }
    else if(i<N4+NW1) m1=fmaxf(m1,fabsf(W1[i-N4]));
    else if(i<N4+NW1+NWC) m2=fmaxf(m2,fabsf(Wc[i-N4-NW1]));
    else m3=fmaxf(m3,fabsf(Wf[i-N4-NW1-NWC]));
  }
  blkStore4(m0,m1,m2,m3,&pt0[blockIdx.x]);
}

__global__ __launch_bounds__(256)
void k_red0(const float4* __restrict__ pt,float* __restrict__ scf){
  int t=threadIdx.x;
  float m0=0.f,m1=0.f,m2=0.f,m3=0.f;
  for(int i=t;i<2048;i+=256){
    float4 v=pt[i];
    m0=fmaxf(m0,v.x);m1=fmaxf(m1,v.y);m2=fmaxf(m2,v.z);m3=fmaxf(m3,v.w);
  }
  #pragma unroll
  for(int off=32;off;off>>=1){
    m0=fmaxf(m0,__shfl_xor(m0,off,64));
    m1=fmaxf(m1,__shfl_xor(m1,off,64));
    m2=fmaxf(m2,__shfl_xor(m2,off,64));
    m3=fmaxf(m3,__shfl_xor(m3,off,64));
  }
  __shared__ float sm[4][4];
  int wid=t>>6;
  if((t&63)==0){sm[wid][0]=m0;sm[wid][1]=m1;sm[wid][2]=m2;sm[wid][3]=m3;}
  __syncthreads();
  if(t==0){
    for(int i=1;i<4;i++){
      m0=fmaxf(m0,sm[i][0]);m1=fmaxf(m1,sm[i][1]);
      m2=fmaxf(m2,sm[i][2]);m3=fmaxf(m3,sm[i][3]);
    }
    scf[0]=fmaxf(m0/127.f,1e-8f);
    scf[1]=fmaxf(m1/3.f,1e-8f);
    scf[2]=fmaxf(m2/3.f,1e-8f);
    scf[3]=fmaxf(m3/3.f,1e-8f);
  }
}

// reduce n float2 partials -> s_pre (preIdx), s_out (outIdx), and 256-entry tanh LUT
__global__ __launch_bounds__(256)
void k_redmm(const float2* __restrict__ pt,int n,float* __restrict__ scf,
             int preIdx,int outIdx,char* __restrict__ lutg){
  int t=threadIdx.x;
  float mn=1e30f,mx=-1e30f;
  for(int i=t;i<n;i+=256){
    float2 v=pt[i];
    mn=fminf(mn,v.x); mx=fmaxf(mx,v.y);
  }
  #pragma unroll
  for(int off=32;off;off>>=1){
    mn=fminf(mn,__shfl_xor(mn,off,64));
    mx=fmaxf(mx,__shfl_xor(mx,off,64));
  }
  __shared__ float smn[4],smx[4];
  __shared__ float bs,bso;
  int wid=t>>6;
  if((t&63)==0){smn[wid]=mn;smx[wid]=mx;}
  __syncthreads();
  if(t==0){
    for(int i=1;i<4;i++){mn=fminf(mn,smn[i]);mx=fmaxf(mx,smx[i]);}
    float ma=fmaxf(fabsf(mn),fabsf(mx));
    float s=fmaxf(ma/127.f,1e-8f);
    float a1=fabsf(fminf(fmaxf(rintf(mn/s),-128.f),127.f)*s);
    float a2=fabsf(fminf(fmaxf(rintf(mx/s),-128.f),127.f)*s);
    float so=fmaxf(tanhf(fmaxf(a1,a2))/127.f,1e-8f);
    scf[preIdx]=s; scf[outIdx]=so;
    bs=s; bso=so;
  }
  __syncthreads();
  float d=(float)(t-128)*bs;
  lutg[t]=(char)(int)fminf(fmaxf(rintf(tanhf(d)/bso),-128.f),127.f);
}

// quantize everything into code tensors
__global__ __launch_bounds__(256)
void k_prep(const float* __restrict__ img,const float* __restrict__ W1,
            const float* __restrict__ Wc,const float* __restrict__ Wf,
            const float* __restrict__ scf,char* __restrict__ wsb){
  float s_img=scf[0], s_w1=scf[1], s_wc=scf[2], s_wf=scf[3];
  float inv_img=1.f/s_img;
  unsigned short* xqb=(unsigned short*)(wsb+B_XQB);
  unsigned short* w1b=(unsigned short*)(wsb+B_W1B);
  char* wcpk=wsb+B_WCQ;
  char* wfb=wsb+B_WFB;
  const int T0=BATCH*LSEQ*32;
  const int T1=T0+MD*32;
  const int T2=T1+MD*16;
  const int T3=T2+168*1024;
  for(int i=blockIdx.x*blockDim.x+threadIdx.x;i<T3;i+=gridDim.x*blockDim.x){
    if(i<T0){
      int row=i>>5, cc=i&31;
      float q = cc<FIN ? fminf(fmaxf(rintf(img[row*FIN+cc]*inv_img),-128.f),127.f) : 0.f;
      xqb[i]=f2bf(q);
    } else if(i<T1){
      int j=i-T0; int o=j>>5, cc=j&31;
      float q = cc<FIN ? fminf(fmaxf(rintf(W1[o*FIN+cc]/s_w1),-4.f),3.f) : 0.f;
      w1b[j]=f2bf(q);
    } else if(i<T2){
      int j=i-T1; int c=j>>4, k=j&15;
      char q=0;
      if(k<KW) q=(char)(int)fminf(fmaxf(rintf(Wc[c*KW+k]/s_wc),-4.f),3.f);
      wcpk[j]=q;
    } else {
      int j=i-T2;
      int s=j>>10, l=(j>>4)&63, jj=j&15;
      int n=l&15, k=s*64+((l>>4)<<4)+jj;
      char q=0;
      if(n<10){
        int c=k/28, ls=k-c*28;
        q=(char)(int)fminf(fmaxf(rintf(Wf[n*10752+ls*MD+c]/s_wf),-4.f),3.f);
      }
      wfb[j]=q;
    }
  }
}

// GEMM1 via bf16 MFMA on integer codes. Block = 4 samples = 112 rows x 384 o.
template<bool WRITE>
__global__ __launch_bounds__(512)
void k_g1(const unsigned short* __restrict__ xqb,const unsigned short* __restrict__ w1b,
          const float* __restrict__ b1,const float* __restrict__ scf,
          const char* __restrict__ lutg,float2* __restrict__ pt1,
          int* __restrict__ bxi){
  __shared__ char ldsraw[43456];
  __shared__ char lut1[256];
  unsigned short* Wlds=(unsigned short*)ldsraw;
  int t=threadIdx.x, wid=t>>6, lane=t&63, l4=lane>>4, l15=lane&15;
  {
    const int* src=(const int*)w1b; int* dst=(int*)ldsraw;
    for(int i=t;i<6144;i+=512) dst[i]=src[i];
  }
  __syncthreads();
  bf16x8 bfr[3]; float b1v[3];
  #pragma unroll
  for(int ni=0;ni<3;ni++){
    int o=(wid*3+ni)*16+l15;
    bfr[ni]=*(const bf16x8*)&Wlds[o*32+l4*8];
    b1v[ni]=b1[o];
  }
  bf16x8 af[7];
  int r0=blockIdx.x*112;
  #pragma unroll
  for(int mt=0;mt<7;mt++)
    af[mt]=*(const bf16x8*)&xqb[(size_t)(r0+mt*16+l15)*32+l4*8];
  float sg=scf[0]*scf[1];
  float inv_lin=1.f;
  if constexpr(WRITE){
    inv_lin=1.f/scf[4];
    if(t<64) ((int*)lut1)[t]=((const int*)lutg)[t];
    __syncthreads();     // Wlds reads done + lut1 visible before reuse as Xt
  }
  char* Xt=ldsraw;
  float mn=1e30f,mx=-1e30f;
  f32x4 zero={0.f,0.f,0.f,0.f};
  #pragma unroll
  for(int ni=0;ni<3;ni++){
    #pragma unroll
    for(int mt=0;mt<7;mt++){
      f32x4 acc=__builtin_amdgcn_mfma_f32_16x16x32_bf16(af[mt],bfr[ni],zero,0,0,0);
      #pragma unroll
      for(int r=0;r<4;r++){
        float v=sg*acc[r]+b1v[ni];
        if constexpr(WRITE){
          int ql=(int)fminf(fmaxf(rintf(v*inv_lin),-128.f),127.f);
          int q=(int)lut1[ql+128];
          int row=mt*16+l4*4+r;
          int o=(wid*3+ni)*16+l15;
          Xt[row*388+o]=(char)q;
        } else {
          mn=fminf(mn,v); mx=fmaxf(mx,v);
        }
      }
    }
  }
  if constexpr(WRITE){
    __syncthreads();
    int b0=blockIdx.x*4;
    for(int i=t;i<10752;i+=512){
      int bl=i/2688, rem=i-bl*2688;
      int o=rem/7, g=rem-o*7;
      int base=(bl*28+g*4)*388+o;
      unsigned w=(unsigned)(unsigned char)Xt[base]
               |((unsigned)(unsigned char)Xt[base+388])<<8
               |((unsigned)(unsigned char)Xt[base+776])<<16
               |((unsigned)(unsigned char)Xt[base+1164])<<24;
      bxi[(size_t)(b0+bl)*2688+o*7+g]=(int)w;
    }
  } else {
    blkStoreMM(mn,mx,&pt1[blockIdx.x]);
  }
}

// depthwise conv, integer dot path. thread = one (b,c) row of packed int8 codes.
template<bool WRITE>
__global__ __launch_bounds__(256)
void k_conv(int* __restrict__ bxi,const char* __restrict__ wcpk,
            const float* __restrict__ bc,const float* __restrict__ scf,
            const char* __restrict__ lutg,float2* __restrict__ pt2){
  __shared__ int rows[1792];
  __shared__ char lut[256];
  int t=threadIdx.x;
  int tid0=blockIdx.x*256;
  int base=tid0*7;
  #pragma unroll
  for(int i=0;i<7;i++) rows[i*256+t]=bxi[base+i*256+t];

  float sfac=scf[5]*scf[2];               // s_o1 * s_wc
  float inv_cv=1.f;
  if constexpr(WRITE){
    inv_cv=1.f/scf[6];
    if(t<64) ((int*)lut)[t]=((const int*)lutg)[t];
  }
  __syncthreads();

  int c=(tid0+t)%MD;
  i32x4 wq=*(const i32x4*)(wcpk+(size_t)c*16);
  float bias=bc[c];
  int ext[11];
  ext[0]=0; ext[1]=0; ext[9]=0; ext[10]=0;
  #pragma unroll
  for(int j=0;j<7;j++) ext[2+j]=rows[t*7+j];

  float mn=1e30f,mx=-1e30f;
  unsigned ow[7];
  #pragma unroll
  for(int l=0;l<LSEQ;l++){
    const int eb=l+1, bi=eb>>2, s=eb&3;
    int A0,A1,A2,A3;
    if(s==0){A0=ext[bi];A1=ext[bi+1];A2=ext[bi+2];A3=ext[bi+3];}
    else{
      A0=ALIGNB(ext[bi+1],ext[bi],s);
      A1=ALIGNB(ext[bi+2],ext[bi+1],s);
      A2=ALIGNB(ext[bi+3],ext[bi+2],s);
      A3=ALIGNB(ext[bi+4],ext[bi+3],s);
    }
    int idot=SDOT4(A0,wq[0],SDOT4(A1,wq[1],SDOT4(A2,wq[2],SDOT4(A3,wq[3],0))));
    float v=fmaf((float)idot,sfac,bias);
    if constexpr(WRITE){
      int qc=(int)fminf(fmaxf(rintf(v*inv_cv),-128.f),127.f);
      unsigned q2=(unsigned)(unsigned char)lut[qc+128];
      if((l&3)==0) ow[l>>2]=q2;
      else ow[l>>2]|=q2<<(8*(l&3));
    } else {
      mn=fminf(mn,v); mx=fmaxf(mx,v);
    }
  }
  if constexpr(WRITE){
    #pragma unroll
    for(int j=0;j<7;j++) rows[t*7+j]=(int)ow[j];
    __syncthreads();
    #pragma unroll
    for(int i=0;i<7;i++) bxi[base+i*256+t]=rows[i*256+t];
  } else {
    blkStoreMM(mn,mx,&pt2[blockIdx.x]);
  }
}

// final linear via i8 MFMA. 256 m-tiles x 4 K-parts, plain-store into slices.
__global__ __launch_bounds__(64)
void k_gemm2(const char* __restrict__ bxb,const char* __restrict__ wfb,
             int* __restrict__ lgint){
  int mt=blockIdx.x>>2, kp=blockIdx.x&3;
  int lane=threadIdx.x, l4=lane>>4, l15=lane&15;
  const char* ap=bxb+(size_t)(mt*16+l15)*10752+l4*16;
  const char* bp=wfb+lane*16;
  i32x4 acc={0,0,0,0};
  int s0=kp*42;
  #pragma unroll 6
  for(int s=s0;s<s0+42;++s){
    i32x4 a=*(const i32x4*)(ap+(size_t)s*64);
    i32x4 b=*(const i32x4*)(bp+(size_t)s*1024);
    acc=__builtin_amdgcn_mfma_i32_16x16x64_i8(a,b,acc,0,0,0);
  }
  int* dst=lgint+kp*65536;
  int rbase=mt*16+l4*4;
  #pragma unroll
  for(int r=0;r<4;r++) dst[(rbase+r)*16+l15]=acc[r];
}

__global__ __launch_bounds__(256)
void k_logmax(const int* __restrict__ lgint,const float* __restrict__ bfv,
              const float* __restrict__ scf,float* __restrict__ lg,
              float* __restrict__ ptl){
  int i=blockIdx.x*256+threadIdx.x;
  float s=scf[3]*scf[7];                  // s_wf * s_o2
  int b=i/10, o=i-b*10;
  int sum=lgint[b*16+o]+lgint[65536+b*16+o]+lgint[131072+b*16+o]+lgint[196608+b*16+o];
  float v=s*(float)sum+bfv[o];
  lg[i]=v;
  float m=fabsf(v);
  #pragma unroll
  for(int off=32;off;off>>=1) m=fmaxf(m,__shfl_xor(m,off,64));
  __shared__ float sm[4];
  int wid=threadIdx.x>>6;
  if((threadIdx.x&63)==0) sm[wid]=m;
  __syncthreads();
  if(threadIdx.x==0){
    for(int k=1;k<4;k++) m=fmaxf(m,sm[k]);
    ptl[blockIdx.x]=m;
  }
}

__global__ __launch_bounds__(256)
void k_final(const float* __restrict__ lg,const float* __restrict__ ptl,
             float* __restrict__ out){
  int t=threadIdx.x;
  float m=(t<160)?ptl[t]:0.f;
  #pragma unroll
  for(int off=32;off;off>>=1) m=fmaxf(m,__shfl_xor(m,off,64));
  __shared__ float sm[4];
  __shared__ float sv;
  int wid=t>>6;
  if((t&63)==0) sm[wid]=m;
  __syncthreads();
  if(t==0){
    for(int k=1;k<4;k++) m=fmaxf(m,sm[k]);
    sv=fmaxf(m/127.f,1e-8f);
  }
  __syncthreads();
  float s=sv;
  int i=blockIdx.x*256+t;
  out[i]=fminf(fmaxf(rintf(lg[i]/s),-128.f),127.f)*s;
}

extern "C" void kernel_launch(void* const* d_in, const int* in_sizes, int n_in,
                              void* d_out, int out_size, void* d_ws, size_t ws_size,
                              hipStream_t stream){
  const float* img=(const float*)d_in[0];
  const float* W1 =(const float*)d_in[1];
  const float* b1 =(const float*)d_in[2];
  const float* Wc =(const float*)d_in[3];
  const float* bc =(const float*)d_in[4];
  const float* Wf =(const float*)d_in[5];
  const float* bf =(const float*)d_in[6];
  float* out=(float*)d_out;
  char* wsb=(char*)d_ws;
  float* scf=(float*)(wsb+B_SCF);
  float4* pt0=(float4*)(wsb+B_PT0);
  float2* pt1=(float2*)(wsb+B_PT1);
  float2* pt2=(float2*)(wsb+B_PT2);
  float* ptl=(float*)(wsb+B_PTL);
  int* lgint=(int*)(wsb+B_LGI);
  float* lg=(float*)(wsb+B_LG);
  int* bxi=(int*)(wsb+B_BX);

  k_maxabs_in<<<2048,256,0,stream>>>(img,W1,Wc,Wf,pt0);
  k_red0<<<1,256,0,stream>>>(pt0,scf);
  k_prep<<<4096,256,0,stream>>>(img,W1,Wc,Wf,scf,wsb);
  k_g1<false><<<1024,512,0,stream>>>((const unsigned short*)(wsb+B_XQB),
                                     (const unsigned short*)(wsb+B_W1B),b1,scf,
                                     nullptr,pt1,nullptr);
  k_redmm<<<1,256,0,stream>>>(pt1,1024,scf,4,5,wsb+B_LUT1);
  k_g1<true ><<<1024,512,0,stream>>>((const unsigned short*)(wsb+B_XQB),
                                     (const unsigned short*)(wsb+B_W1B),b1,scf,
                                     wsb+B_LUT1,nullptr,bxi);
  k_conv<false><<<6144,256,0,stream>>>(bxi,wsb+B_WCQ,bc,scf,nullptr,pt2);
  k_redmm<<<1,256,0,stream>>>(pt2,6144,scf,6,7,wsb+B_LUT2);
  k_conv<true ><<<6144,256,0,stream>>>(bxi,wsb+B_WCQ,bc,scf,wsb+B_LUT2,nullptr);
  k_gemm2<<<1024,64,0,stream>>>((const char*)bxi,wsb+B_WFB,lgint);
  k_logmax<<<160,256,0,stream>>>(lgint,bf,scf,lg,ptl);
  k_final<<<160,256,0,stream>>>(lg,ptl,out);
}

// Round 5
// 107.744 us; speedup vs baseline: 9.4179x; 1.0976x over previous
//
#include <hip/hip_runtime.h>

#define BATCH 4096
#define MD 384
#define KW 15
#define PADW 7
#define LSEQ 28
#define FIN 28

#define NX (BATCH*LSEQ*FIN)

// scf slots: 0 s_img, 1 s_w1, 2 s_wc, 3 s_wf, 4 s_lin, 5 s_o1, 6 s_cv, 7 s_o2

// workspace layout (byte offsets, 16B-aligned)
#define B_SCF  0
#define B_LUT1 256
#define B_LUT2 512
#define B_PT0  1024      // 2048 float4
#define B_PT1  33792     // 1024 float2
#define B_PT2  41984     // 1024 float2
#define B_PTL  50176     // 1024 float
#define B_W1B  54272     // MD*32 bf16 = 24576
#define B_WCQ  78848     // MD*16 i8 = 6144
#define B_WFB  84992     // 10*10752 i8 = 107520
#define B_LG   192512    // 40960 float
#define B_XQB  356352    // BATCH*28*32 bf16 = 7340032

typedef __bf16 bf16x8 __attribute__((ext_vector_type(8)));
typedef float f32x4 __attribute__((ext_vector_type(4)));
typedef int i32x4 __attribute__((ext_vector_type(4)));

#if __has_builtin(__builtin_amdgcn_sdot4)
#define SDOT4(a,b,c) __builtin_amdgcn_sdot4((a),(b),(c),false)
#else
__device__ __forceinline__ int SDOT4(int a,int b,int c){
  c += ((a<<24)>>24)*((b<<24)>>24);
  c += ((a<<16)>>24)*((b<<16)>>24);
  c += ((a<<8)>>24)*((b<<8)>>24);
  c += (a>>24)*(b>>24);
  return c;
}
#endif

#if __has_builtin(__builtin_amdgcn_alignbyte)
#define ALIGNB(hi,lo,s) __builtin_amdgcn_alignbyte((hi),(lo),(s))
#else
#define ALIGNB(hi,lo,s) ((int)(((unsigned)(lo)>>(8*(s)))|((unsigned)(hi)<<(32-8*(s)))))
#endif

__device__ __forceinline__ unsigned short f2bf(float f){
  return (unsigned short)(__float_as_uint(f)>>16);   // exact for small ints
}

__device__ __forceinline__ void blkStore4(float m0,float m1,float m2,float m3,float4* dst){
  #pragma unroll
  for(int off=32;off;off>>=1){
    m0=fmaxf(m0,__shfl_xor(m0,off,64));
    m1=fmaxf(m1,__shfl_xor(m1,off,64));
    m2=fmaxf(m2,__shfl_xor(m2,off,64));
    m3=fmaxf(m3,__shfl_xor(m3,off,64));
  }
  __shared__ float sm[4][4];
  int wid=threadIdx.x>>6;
  if((threadIdx.x&63)==0){sm[wid][0]=m0;sm[wid][1]=m1;sm[wid][2]=m2;sm[wid][3]=m3;}
  __syncthreads();
  if(threadIdx.x==0){
    for(int i=1;i<4;i++){
      m0=fmaxf(m0,sm[i][0]);m1=fmaxf(m1,sm[i][1]);
      m2=fmaxf(m2,sm[i][2]);m3=fmaxf(m3,sm[i][3]);
    }
    *dst=make_float4(m0,m1,m2,m3);
  }
}

__device__ __forceinline__ void blkStoreMM(float mn,float mx,float2* dst){
  #pragma unroll
  for(int off=32;off;off>>=1){
    mn=fminf(mn,__shfl_xor(mn,off,64));
    mx=fmaxf(mx,__shfl_xor(mx,off,64));
  }
  __shared__ float smn[8],smx[8];
  int wid=threadIdx.x>>6, nw=blockDim.x>>6;
  if((threadIdx.x&63)==0){smn[wid]=mn;smx[wid]=mx;}
  __syncthreads();
  if(threadIdx.x==0){
    for(int i=1;i<nw;i++){mn=fminf(mn,smn[i]);mx=fmaxf(mx,smx[i]);}
    *dst=make_float2(mn,mx);
  }
}

// ---------- small kernels ----------
__global__ __launch_bounds__(256)
void k_maxabs_in(const float* __restrict__ img,const float* __restrict__ W1,
                 const float* __restrict__ Wc,const float* __restrict__ Wf,
                 float4* __restrict__ pt0){
  float m0=0.f,m1=0.f,m2=0.f,m3=0.f;
  const int N4=NX/4;
  const int NW1=MD*FIN, NWC=MD*KW, NWF=10*MD*LSEQ;
  const int total=N4+NW1+NWC+NWF;
  const float4* img4=(const float4*)img;
  for(int i=blockIdx.x*blockDim.x+threadIdx.x;i<total;i+=gridDim.x*blockDim.x){
    if(i<N4){
      float4 v=img4[i];
      m0=fmaxf(m0,fmaxf(fmaxf(fabsf(v.x),fabsf(v.y)),fmaxf(fabsf(v.z),fabsf(v.w))));
    }
    else if(i<N4+NW1) m1=fmaxf(m1,fabsf(W1[i-N4]));
    else if(i<N4+NW1+NWC) m2=fmaxf(m2,fabsf(Wc[i-N4-NW1]));
    else m3=fmaxf(m3,fabsf(Wf[i-N4-NW1-NWC]));
  }
  blkStore4(m0,m1,m2,m3,&pt0[blockIdx.x]);
}

__global__ __launch_bounds__(256)
void k_red0(const float4* __restrict__ pt,float* __restrict__ scf){
  int t=threadIdx.x;
  float m0=0.f,m1=0.f,m2=0.f,m3=0.f;
  for(int i=t;i<2048;i+=256){
    float4 v=pt[i];
    m0=fmaxf(m0,v.x);m1=fmaxf(m1,v.y);m2=fmaxf(m2,v.z);m3=fmaxf(m3,v.w);
  }
  #pragma unroll
  for(int off=32;off;off>>=1){
    m0=fmaxf(m0,__shfl_xor(m0,off,64));
    m1=fmaxf(m1,__shfl_xor(m1,off,64));
    m2=fmaxf(m2,__shfl_xor(m2,off,64));
    m3=fmaxf(m3,__shfl_xor(m3,off,64));
  }
  __shared__ float sm[4][4];
  int wid=t>>6;
  if((t&63)==0){sm[wid][0]=m0;sm[wid][1]=m1;sm[wid][2]=m2;sm[wid][3]=m3;}
  __syncthreads();
  if(t==0){
    for(int i=1;i<4;i++){
      m0=fmaxf(m0,sm[i][0]);m1=fmaxf(m1,sm[i][1]);
      m2=fmaxf(m2,sm[i][2]);m3=fmaxf(m3,sm[i][3]);
    }
    scf[0]=fmaxf(m0/127.f,1e-8f);
    scf[1]=fmaxf(m1/3.f,1e-8f);
    scf[2]=fmaxf(m2/3.f,1e-8f);
    scf[3]=fmaxf(m3/3.f,1e-8f);
  }
}

__global__ __launch_bounds__(256)
void k_redmm(const float2* __restrict__ pt,int n,float* __restrict__ scf,
             int preIdx,int outIdx,char* __restrict__ lutg){
  int t=threadIdx.x;
  float mn=1e30f,mx=-1e30f;
  for(int i=t;i<n;i+=256){
    float2 v=pt[i];
    mn=fminf(mn,v.x); mx=fmaxf(mx,v.y);
  }
  #pragma unroll
  for(int off=32;off;off>>=1){
    mn=fminf(mn,__shfl_xor(mn,off,64));
    mx=fmaxf(mx,__shfl_xor(mx,off,64));
  }
  __shared__ float smn[4],smx[4];
  __shared__ float bs,bso;
  int wid=t>>6;
  if((t&63)==0){smn[wid]=mn;smx[wid]=mx;}
  __syncthreads();
  if(t==0){
    for(int i=1;i<4;i++){mn=fminf(mn,smn[i]);mx=fmaxf(mx,smx[i]);}
    float ma=fmaxf(fabsf(mn),fabsf(mx));
    float s=fmaxf(ma/127.f,1e-8f);
    float a1=fabsf(fminf(fmaxf(rintf(mn/s),-128.f),127.f)*s);
    float a2=fabsf(fminf(fmaxf(rintf(mx/s),-128.f),127.f)*s);
    float so=fmaxf(tanhf(fmaxf(a1,a2))/127.f,1e-8f);
    scf[preIdx]=s; scf[outIdx]=so;
    bs=s; bso=so;
  }
  __syncthreads();
  float d=(float)(t-128)*bs;
  lutg[t]=(char)(int)fminf(fmaxf(rintf(tanhf(d)/bso),-128.f),127.f);
}

// quantize inputs into code tensors
__global__ __launch_bounds__(256)
void k_prep(const float* __restrict__ img,const float* __restrict__ W1,
            const float* __restrict__ Wc,const float* __restrict__ Wf,
            const float* __restrict__ scf,char* __restrict__ wsb){
  float s_img=scf[0], s_w1=scf[1], s_wc=scf[2], s_wf=scf[3];
  float inv_img=1.f/s_img;
  unsigned short* xqb=(unsigned short*)(wsb+B_XQB);
  unsigned short* w1b=(unsigned short*)(wsb+B_W1B);
  char* wcpk=wsb+B_WCQ;
  char* wfb=wsb+B_WFB;
  const int T0=BATCH*LSEQ*32;
  const int T1=T0+MD*32;
  const int T2=T1+MD*16;
  const int T3=T2+10*10752;
  for(int i=blockIdx.x*blockDim.x+threadIdx.x;i<T3;i+=gridDim.x*blockDim.x){
    if(i<T0){
      int row=i>>5, cc=i&31;
      float q = cc<FIN ? fminf(fmaxf(rintf(img[row*FIN+cc]*inv_img),-128.f),127.f) : 0.f;
      xqb[i]=f2bf(q);
    } else if(i<T1){
      int j=i-T0; int o=j>>5, cc=j&31;
      float q = cc<FIN ? fminf(fmaxf(rintf(W1[o*FIN+cc]/s_w1),-4.f),3.f) : 0.f;
      w1b[j]=f2bf(q);
    } else if(i<T2){
      int j=i-T1; int c=j>>4, k=j&15;
      char q=0;
      if(k<KW) q=(char)(int)fminf(fmaxf(rintf(Wc[c*KW+k]/s_wc),-4.f),3.f);
      wcpk[j]=q;
    } else {
      int j=i-T2;                 // [0, 107520): wfb[n][c*28+l]
      int n=j/10752, r=j-n*10752;
      int c=r/28, l=r-c*28;
      wfb[j]=(char)(int)fminf(fmaxf(rintf(Wf[n*10752+l*MD+c]/s_wf),-4.f),3.f);
    }
  }
}

// Fused block = 4 samples. MODE 0: lin minmax. MODE 1: lin->codes->conv minmax.
// MODE 2: lin->conv codes->in-block gemm2 -> logits + block max partial.
template<int MODE>
__global__ __launch_bounds__(512)
void k_fused(const unsigned short* __restrict__ xqb,const unsigned short* __restrict__ w1b,
             const float* __restrict__ b1,const float* __restrict__ scf,
             const char* __restrict__ lut1g,const char* __restrict__ lut2g,
             const char* __restrict__ wcpk,const float* __restrict__ bc,
             const int* __restrict__ wfw,const float* __restrict__ bfv,
             float2* __restrict__ ptmm,float* __restrict__ lg,
             float* __restrict__ ptl){
  __shared__ int ldsI[10752];          // Wlds -> lin codes Cw -> conv codes Dw
  __shared__ int psum[10][4][7];
  __shared__ char lutA[256];
  __shared__ char lutB[256];
  int t=threadIdx.x, wid=t>>6, lane=t&63, l4=lane>>4, l15=lane&15;
  {
    const int* src=(const int*)w1b;
    for(int i=t;i<6144;i+=512) ldsI[i]=src[i];
  }
  __syncthreads();
  unsigned short* Wlds=(unsigned short*)ldsI;
  bf16x8 bfr[3]; float b1v[3];
  #pragma unroll
  for(int ni=0;ni<3;ni++){
    int o=(wid*3+ni)*16+l15;
    bfr[ni]=*(const bf16x8*)&Wlds[o*32+l4*8];
    b1v[ni]=b1[o];
  }
  bf16x8 af[7];
  int r0=blockIdx.x*112;
  #pragma unroll
  for(int mt=0;mt<7;mt++)
    af[mt]=*(const bf16x8*)&xqb[(size_t)(r0+mt*16+l15)*32+l4*8];
  float sg=scf[0]*scf[1];
  float inv_lin=1.f, inv_cv=1.f, sfac=1.f, gsc=1.f;
  if constexpr(MODE>=1){
    inv_lin=1.f/scf[4];
    sfac=scf[5]*scf[2];                 // s_o1 * s_wc
    if(t<64) ((int*)lutA)[t]=((const int*)lut1g)[t];
  }
  if constexpr(MODE==2){
    inv_cv=1.f/scf[6];
    gsc=scf[3]*scf[7];                  // s_wf * s_o2
    if(t>=64&&t<128) ((int*)lutB)[t-64]=((const int*)lut2g)[t-64];
  }
  if constexpr(MODE>=1) __syncthreads(); // Wlds reads done before Cw overwrite

  float mn=1e30f,mx=-1e30f;
  f32x4 zero={0.f,0.f,0.f,0.f};
  #pragma unroll
  for(int ni=0;ni<3;ni++){
    int o=(wid*3+ni)*16+l15;
    #pragma unroll
    for(int mt=0;mt<7;mt++){
      f32x4 acc=__builtin_amdgcn_mfma_f32_16x16x32_bf16(af[mt],bfr[ni],zero,0,0,0);
      if constexpr(MODE==0){
        #pragma unroll
        for(int r=0;r<4;r++){
          float v=sg*acc[r]+b1v[ni];
          mn=fminf(mn,v); mx=fmaxf(mx,v);
        }
      } else {
        unsigned w=0;
        #pragma unroll
        for(int r=0;r<4;r++){
          float v=sg*acc[r]+b1v[ni];
          int ql=(int)fminf(fmaxf(rintf(v*inv_lin),-128.f),127.f);
          unsigned q=(unsigned)(unsigned char)lutA[ql+128];
          w|=q<<(8*r);
        }
        ldsI[o*28+mt*4+l4]=(int)w;       // Cw[o][word]
      }
    }
  }
  if constexpr(MODE==0){
    blkStoreMM(mn,mx,&ptmm[blockIdx.x]);
    return;
  }
  __syncthreads();

  // depthwise conv: 1536 rows (s,c), 3 per thread
  int oww[3][7];
  float mnc=1e30f,mxc=-1e30f;
  #pragma unroll
  for(int rr=0;rr<3;rr++){
    int j=t+rr*512;
    int s=j/384, c=j-s*384;
    i32x4 wq=*(const i32x4*)(wcpk+(size_t)c*16);
    float bias=bc[c];
    int ext[11];
    ext[0]=0; ext[1]=0; ext[9]=0; ext[10]=0;
    #pragma unroll
    for(int i=0;i<7;i++) ext[2+i]=ldsI[c*28+s*7+i];
    #pragma unroll
    for(int l=0;l<LSEQ;l++){
      const int eb=l+1, bi=eb>>2, sh=eb&3;
      int A0,A1,A2,A3;
      if(sh==0){A0=ext[bi];A1=ext[bi+1];A2=ext[bi+2];A3=ext[bi+3];}
      else{
        A0=ALIGNB(ext[bi+1],ext[bi],sh);
        A1=ALIGNB(ext[bi+2],ext[bi+1],sh);
        A2=ALIGNB(ext[bi+3],ext[bi+2],sh);
        A3=ALIGNB(ext[bi+4],ext[bi+3],sh);
      }
      int idot=SDOT4(A0,wq[0],SDOT4(A1,wq[1],SDOT4(A2,wq[2],SDOT4(A3,wq[3],0))));
      float v=fmaf((float)idot,sfac,bias);
      if constexpr(MODE==1){
        mnc=fminf(mnc,v); mxc=fmaxf(mxc,v);
      } else {
        int qc=(int)fminf(fmaxf(rintf(v*inv_cv),-128.f),127.f);
        unsigned q2=(unsigned)(unsigned char)lutB[qc+128];
        if((l&3)==0) oww[rr][l>>2]=(int)q2;
        else oww[rr][l>>2]|=(int)(q2<<(8*(l&3)));
      }
    }
  }
  if constexpr(MODE==1){
    blkStoreMM(mnc,mxc,&ptmm[blockIdx.x]);
    return;
  }

  // MODE 2: rewrite conv codes sample-major Dw[s][c*7+i], then in-block gemm2
  __syncthreads();
  #pragma unroll
  for(int rr=0;rr<3;rr++){
    int j=t+rr*512;
    int s=j/384, c=j-s*384;
    #pragma unroll
    for(int i=0;i<7;i++) ldsI[s*2688+c*7+i]=oww[rr][i];
  }
  __syncthreads();

  if(t<448){
    int cwv[24];
    #pragma unroll
    for(int s=0;s<4;s++)
      #pragma unroll
      for(int j6=0;j6<6;j6++) cwv[s*6+j6]=ldsI[s*2688+j6*448+t];
    #pragma unroll
    for(int o=0;o<10;o++){
      int a0=0,a1=0,a2=0,a3=0;
      #pragma unroll
      for(int j6=0;j6<6;j6++){
        int wfv=wfw[o*2688+j6*448+t];
        a0=SDOT4(cwv[0*6+j6],wfv,a0);
        a1=SDOT4(cwv[1*6+j6],wfv,a1);
        a2=SDOT4(cwv[2*6+j6],wfv,a2);
        a3=SDOT4(cwv[3*6+j6],wfv,a3);
      }
      #pragma unroll
      for(int off=32;off;off>>=1){
        a0+=__shfl_xor(a0,off,64);
        a1+=__shfl_xor(a1,off,64);
        a2+=__shfl_xor(a2,off,64);
        a3+=__shfl_xor(a3,off,64);
      }
      if(lane==0){
        psum[o][0][wid]=a0; psum[o][1][wid]=a1;
        psum[o][2][wid]=a2; psum[o][3][wid]=a3;
      }
    }
  }
  __syncthreads();
  float m=0.f;
  if(t<40){
    int s=t/10, o=t-s*10;
    int sum=0;
    #pragma unroll
    for(int i=0;i<7;i++) sum+=psum[o][s][i];
    float v=fmaf((float)sum,gsc,bfv[o]);
    lg[(blockIdx.x*4+s)*10+o]=v;
    m=fabsf(v);
  }
  if(t<64){
    #pragma unroll
    for(int off=32;off;off>>=1) m=fmaxf(m,__shfl_xor(m,off,64));
    if(t==0) ptl[blockIdx.x]=m;
  }
}

__global__ __launch_bounds__(256)
void k_final(const float* __restrict__ lg,const float* __restrict__ ptl,
             float* __restrict__ out){
  int t=threadIdx.x;
  float m=0.f;
  for(int i=t;i<1024;i+=256) m=fmaxf(m,ptl[i]);
  #pragma unroll
  for(int off=32;off;off>>=1) m=fmaxf(m,__shfl_xor(m,off,64));
  __shared__ float sm[4];
  __shared__ float sv;
  int wid=t>>6;
  if((t&63)==0) sm[wid]=m;
  __syncthreads();
  if(t==0){
    for(int k=1;k<4;k++) m=fmaxf(m,sm[k]);
    sv=fmaxf(m/127.f,1e-8f);
  }
  __syncthreads();
  float s=sv;
  int i=blockIdx.x*256+t;
  out[i]=fminf(fmaxf(rintf(lg[i]/s),-128.f),127.f)*s;
}

extern "C" void kernel_launch(void* const* d_in, const int* in_sizes, int n_in,
                              void* d_out, int out_size, void* d_ws, size_t ws_size,
                              hipStream_t stream){
  const float* img=(const float*)d_in[0];
  const float* W1 =(const float*)d_in[1];
  const float* b1 =(const float*)d_in[2];
  const float* Wc =(const float*)d_in[3];
  const float* bc =(const float*)d_in[4];
  const float* Wf =(const float*)d_in[5];
  const float* bf =(const float*)d_in[6];
  float* out=(float*)d_out;
  char* wsb=(char*)d_ws;
  float* scf=(float*)(wsb+B_SCF);
  float4* pt0=(float4*)(wsb+B_PT0);
  float2* pt1=(float2*)(wsb+B_PT1);
  float2* pt2=(float2*)(wsb+B_PT2);
  float* ptl=(float*)(wsb+B_PTL);
  float* lg=(float*)(wsb+B_LG);
  const unsigned short* xqb=(const unsigned short*)(wsb+B_XQB);
  const unsigned short* w1b=(const unsigned short*)(wsb+B_W1B);
  const char* wcpk=wsb+B_WCQ;
  const int* wfw=(const int*)(wsb+B_WFB);

  k_maxabs_in<<<2048,256,0,stream>>>(img,W1,Wc,Wf,pt0);
  k_red0<<<1,256,0,stream>>>(pt0,scf);
  k_prep<<<4096,256,0,stream>>>(img,W1,Wc,Wf,scf,wsb);
  k_fused<0><<<1024,512,0,stream>>>(xqb,w1b,b1,scf,nullptr,nullptr,wcpk,bc,wfw,bf,pt1,nullptr,nullptr);
  k_redmm<<<1,256,0,stream>>>(pt1,1024,scf,4,5,wsb+B_LUT1);
  k_fused<1><<<1024,512,0,stream>>>(xqb,w1b,b1,scf,wsb+B_LUT1,nullptr,wcpk,bc,wfw,bf,pt2,nullptr,nullptr);
  k_redmm<<<1,256,0,stream>>>(pt2,1024,scf,6,7,wsb+B_LUT2);
  k_fused<2><<<1024,512,0,stream>>>(xqb,w1b,b1,scf,wsb+B_LUT1,wsb+B_LUT2,wcpk,bc,wfw,bf,nullptr,lg,ptl);
  k_final<<<160,256,0,stream>>>(lg,ptl,out);
}

// Round 9
// 105.577 us; speedup vs baseline: 9.6112x; 1.0205x over previous
//
#include <hip/hip_runtime.h>

#define BATCH 4096
#define MD 384
#define KW 15
#define PADW 7
#define LSEQ 28
#define FIN 28

#define NX (BATCH*LSEQ*FIN)

// scf slots: 0 s_img, 1 s_w1, 2 s_wc, 3 s_wf, 4 s_lin, 5 s_o1, 6 s_cv, 7 s_o2

// workspace layout (byte offsets, 16B-aligned)
#define B_SCF  0
#define B_LUT1 256
#define B_LUT2 512
#define B_PT0  1024      // 2048 float4 -> ends 33792
#define B_PT1  33792     // 1024 float2
#define B_PT2  41984     // 1024 float2
#define B_PTL  50176     // 1024 float
#define B_W1B  54272     // MD*32 bf16 = 24576
#define B_WCQ  78848     // MD*16 i8 = 6144
#define B_WFB  84992     // 16*10752 i8 = 172032 (rows 10..15 uninit pad, cols ignored)
#define B_LG   257024    // 40960 float
#define B_XQB  420864    // BATCH*28*32 bf16 = 7340032

typedef __bf16 bf16x8 __attribute__((ext_vector_type(8)));
typedef float f32x4 __attribute__((ext_vector_type(4)));
typedef int i32x4 __attribute__((ext_vector_type(4)));

#if __has_builtin(__builtin_amdgcn_sdot4)
#define SDOT4(a,b,c) __builtin_amdgcn_sdot4((a),(b),(c),false)
#else
__device__ __forceinline__ int SDOT4(int a,int b,int c){
  c += ((a<<24)>>24)*((b<<24)>>24);
  c += ((a<<16)>>24)*((b<<16)>>24);
  c += ((a<<8)>>24)*((b<<8)>>24);
  c += (a>>24)*(b>>24);
  return c;
}
#endif

#if __has_builtin(__builtin_amdgcn_alignbyte)
#define ALIGNB(hi,lo,s) __builtin_amdgcn_alignbyte((hi),(lo),(s))
#else
#define ALIGNB(hi,lo,s) ((int)(((unsigned)(lo)>>(8*(s)))|((unsigned)(hi)<<(32-8*(s)))))
#endif

__device__ __forceinline__ unsigned short f2bf(float f){
  return (unsigned short)(__float_as_uint(f)>>16);   // exact for small ints
}

// LUT lookup via ds_bpermute: 256-B table held as 1 int/lane across the wave.
__device__ __forceinline__ unsigned lut_bperm(int iw,int lutw){
  int res=__builtin_amdgcn_ds_bpermute(iw,lutw);    // lane = iw>>2
  return ((unsigned)res>>(8*(iw&3)))&0xFFu;
}

__device__ __forceinline__ void blkStore4(float m0,float m1,float m2,float m3,float4* dst){
  #pragma unroll
  for(int off=32;off;off>>=1){
    m0=fmaxf(m0,__shfl_xor(m0,off,64));
    m1=fmaxf(m1,__shfl_xor(m1,off,64));
    m2=fmaxf(m2,__shfl_xor(m2,off,64));
    m3=fmaxf(m3,__shfl_xor(m3,off,64));
  }
  __shared__ float sm[4][4];
  int wid=threadIdx.x>>6;
  if((threadIdx.x&63)==0){sm[wid][0]=m0;sm[wid][1]=m1;sm[wid][2]=m2;sm[wid][3]=m3;}
  __syncthreads();
  if(threadIdx.x==0){
    for(int i=1;i<4;i++){
      m0=fmaxf(m0,sm[i][0]);m1=fmaxf(m1,sm[i][1]);
      m2=fmaxf(m2,sm[i][2]);m3=fmaxf(m3,sm[i][3]);
    }
    *dst=make_float4(m0,m1,m2,m3);
  }
}

__device__ __forceinline__ void blkStoreMM(float mn,float mx,float2* dst){
  #pragma unroll
  for(int off=32;off;off>>=1){
    mn=fminf(mn,__shfl_xor(mn,off,64));
    mx=fmaxf(mx,__shfl_xor(mx,off,64));
  }
  __shared__ float smn[8],smx[8];
  int wid=threadIdx.x>>6, nw=blockDim.x>>6;
  if((threadIdx.x&63)==0){smn[wid]=mn;smx[wid]=mx;}
  __syncthreads();
  if(threadIdx.x==0){
    for(int i=1;i<nw;i++){mn=fminf(mn,smn[i]);mx=fmaxf(mx,smx[i]);}
    *dst=make_float2(mn,mx);
  }
}

// ---------- small kernels ----------
__global__ __launch_bounds__(256)
void k_maxabs_in(const float* __restrict__ img,const float* __restrict__ W1,
                 const float* __restrict__ Wc,const float* __restrict__ Wf,
                 float4* __restrict__ pt0){
  float m0=0.f,m1=0.f,m2=0.f,m3=0.f;
  const int N4=NX/4;
  const int NW1=MD*FIN, NWC=MD*KW, NWF=10*MD*LSEQ;
  const int total=N4+NW1+NWC+NWF;
  const float4* img4=(const float4*)img;
  for(int i=blockIdx.x*blockDim.x+threadIdx.x;i<total;i+=gridDim.x*blockDim.x){
    if(i<N4){
      float4 v=img4[i];
      m0=fmaxf(m0,fmaxf(fmaxf(fabsf(v.x),fabsf(v.y)),fmaxf(fabsf(v.z),fabsf(v.w))));
    }
    else if(i<N4+NW1) m1=fmaxf(m1,fabsf(W1[i-N4]));
    else if(i<N4+NW1+NWC) m2=fmaxf(m2,fabsf(Wc[i-N4-NW1]));
    else m3=fmaxf(m3,fabsf(Wf[i-N4-NW1-NWC]));
  }
  blkStore4(m0,m1,m2,m3,&pt0[blockIdx.x]);
}

__global__ __launch_bounds__(256)
void k_red0(const float4* __restrict__ pt,float* __restrict__ scf){
  int t=threadIdx.x;
  float m0=0.f,m1=0.f,m2=0.f,m3=0.f;
  for(int i=t;i<2048;i+=256){
    float4 v=pt[i];
    m0=fmaxf(m0,v.x);m1=fmaxf(m1,v.y);m2=fmaxf(m2,v.z);m3=fmaxf(m3,v.w);
  }
  #pragma unroll
  for(int off=32;off;off>>=1){
    m0=fmaxf(m0,__shfl_xor(m0,off,64));
    m1=fmaxf(m1,__shfl_xor(m1,off,64));
    m2=fmaxf(m2,__shfl_xor(m2,off,64));
    m3=fmaxf(m3,__shfl_xor(m3,off,64));
  }
  __shared__ float sm[4][4];
  int wid=t>>6;
  if((t&63)==0){sm[wid][0]=m0;sm[wid][1]=m1;sm[wid][2]=m2;sm[wid][3]=m3;}
  __syncthreads();
  if(t==0){
    for(int i=1;i<4;i++){
      m0=fmaxf(m0,sm[i][0]);m1=fmaxf(m1,sm[i][1]);
      m2=fmaxf(m2,sm[i][2]);m3=fmaxf(m3,sm[i][3]);
    }
    scf[0]=fmaxf(m0/127.f,1e-8f);
    scf[1]=fmaxf(m1/3.f,1e-8f);
    scf[2]=fmaxf(m2/3.f,1e-8f);
    scf[3]=fmaxf(m3/3.f,1e-8f);
  }
}

__global__ __launch_bounds__(256)
void k_redmm(const float2* __restrict__ pt,int n,float* __restrict__ scf,
             int preIdx,int outIdx,char* __restrict__ lutg){
  int t=threadIdx.x;
  float mn=1e30f,mx=-1e30f;
  for(int i=t;i<n;i+=256){
    float2 v=pt[i];
    mn=fminf(mn,v.x); mx=fmaxf(mx,v.y);
  }
  #pragma unroll
  for(int off=32;off;off>>=1){
    mn=fminf(mn,__shfl_xor(mn,off,64));
    mx=fmaxf(mx,__shfl_xor(mx,off,64));
  }
  __shared__ float smn[4],smx[4];
  __shared__ float bs,bso;
  int wid=t>>6;
  if((t&63)==0){smn[wid]=mn;smx[wid]=mx;}
  __syncthreads();
  if(t==0){
    for(int i=1;i<4;i++){mn=fminf(mn,smn[i]);mx=fmaxf(mx,smx[i]);}
    float ma=fmaxf(fabsf(mn),fabsf(mx));
    float s=fmaxf(ma/127.f,1e-8f);
    float a1=fabsf(fminf(fmaxf(rintf(mn/s),-128.f),127.f)*s);
    float a2=fabsf(fminf(fmaxf(rintf(mx/s),-128.f),127.f)*s);
    float so=fmaxf(tanhf(fmaxf(a1,a2))/127.f,1e-8f);
    scf[preIdx]=s; scf[outIdx]=so;
    bs=s; bso=so;
  }
  __syncthreads();
  float d=(float)(t-128)*bs;
  lutg[t]=(char)(int)fminf(fmaxf(rintf(tanhf(d)/bso),-128.f),127.f);
}

// quantize inputs into code tensors
__global__ __launch_bounds__(256)
void k_prep(const float* __restrict__ img,const float* __restrict__ W1,
            const float* __restrict__ Wc,const float* __restrict__ Wf,
            const float* __restrict__ scf,char* __restrict__ wsb){
  float s_img=scf[0], s_w1=scf[1], s_wc=scf[2], s_wf=scf[3];
  float inv_img=1.f/s_img;
  unsigned short* xqb=(unsigned short*)(wsb+B_XQB);
  unsigned short* w1b=(unsigned short*)(wsb+B_W1B);
  char* wcpk=wsb+B_WCQ;
  char* wfb=wsb+B_WFB;
  const int T0=BATCH*LSEQ*32;
  const int T1=T0+MD*32;
  const int T2=T1+MD*16;
  const int T3=T2+10*10752;
  for(int i=blockIdx.x*blockDim.x+threadIdx.x;i<T3;i+=gridDim.x*blockDim.x){
    if(i<T0){
      int row=i>>5, cc=i&31;
      float q = cc<FIN ? fminf(fmaxf(rintf(img[row*FIN+cc]*inv_img),-128.f),127.f) : 0.f;
      xqb[i]=f2bf(q);
    } else if(i<T1){
      int j=i-T0; int o=j>>5, cc=j&31;
      float q = cc<FIN ? fminf(fmaxf(rintf(W1[o*FIN+cc]/s_w1),-4.f),3.f) : 0.f;
      w1b[j]=f2bf(q);
    } else if(i<T2){
      int j=i-T1; int c=j>>4, k=j&15;
      char q=0;
      if(k<KW) q=(char)(int)fminf(fmaxf(rintf(Wc[c*KW+k]/s_wc),-4.f),3.f);
      wcpk[j]=q;
    } else {
      int j=i-T2;                 // [0, 107520): wfb[n][c*28+l]
      int n=j/10752, r=j-n*10752;
      int c=r/28, l=r-c*28;
      wfb[j]=(char)(int)fminf(fmaxf(rintf(Wf[n*10752+l*MD+c]/s_wf),-4.f),3.f);
    }
  }
}

// Fused block = 4 samples (112 rows x 384 o).
// MODE 0: lin minmax. MODE 1: lin codes -> conv minmax.
// MODE 2: lin codes -> conv codes -> in-block i8-MFMA gemm2 -> logits + max partial.
#define CWS 29          // padded Cw row stride (ints), coprime with 32
#define DWS 2692        // Dw sample stride in INTS (2688 data + 4 pad) = 10768 B
template<int MODE>
__global__ __launch_bounds__(512)
void k_fused(const unsigned short* __restrict__ xqb,const unsigned short* __restrict__ w1b,
             const float* __restrict__ b1,const float* __restrict__ scf,
             const char* __restrict__ lut1g,const char* __restrict__ lut2g,
             const char* __restrict__ wcpk,const float* __restrict__ bc,
             const char* __restrict__ wfb,const float* __restrict__ bfv,
             float2* __restrict__ ptmm,float* __restrict__ lg,
             float* __restrict__ ptl){
  __shared__ int ldsI[MD*CWS];         // Wlds(6144) -> Cw[384][29] -> Dw 4xDWS overlay
  __shared__ int psumN[8][10][4];
  int t=threadIdx.x, wid=t>>6, lane=t&63, l4=lane>>4, l15=lane&15;
  {
    const int* src=(const int*)w1b;
    for(int i=t;i<6144;i+=512) ldsI[i]=src[i];
  }
  __syncthreads();
  unsigned short* Wlds=(unsigned short*)ldsI;
  bf16x8 bfr[3]; float b1v[3];
  #pragma unroll
  for(int ni=0;ni<3;ni++){
    int o=(wid*3+ni)*16+l15;
    bfr[ni]=*(const bf16x8*)&Wlds[o*32+l4*8];
    b1v[ni]=b1[o];
  }
  bf16x8 af[7];
  int r0=blockIdx.x*112;
  #pragma unroll
  for(int mt=0;mt<7;mt++)
    af[mt]=*(const bf16x8*)&xqb[(size_t)(r0+mt*16+l15)*32+l4*8];
  float sg=scf[0]*scf[1];
  float sgi=sg, b1s[3]={0.f,0.f,0.f};
  int lutA_w=0,lutB_w=0;
  float ck1=1.f,inv_cv=1.f,sfac=1.f,gsc=1.f;
  if constexpr(MODE>=1){
    float inv_lin=1.f/scf[4];
    sgi=sg*inv_lin;
    #pragma unroll
    for(int ni=0;ni<3;ni++) b1s[ni]=fmaf(b1v[ni],inv_lin,128.f);
    lutA_w=((const int*)lut1g)[lane];
    sfac=scf[5]*scf[2];                 // s_o1 * s_wc
  }
  if constexpr(MODE==2){
    inv_cv=1.f/scf[6];
    ck1=sfac*inv_cv;                    // idot -> quant domain
    gsc=scf[3]*scf[7];                  // s_wf * s_o2
    lutB_w=((const int*)lut2g)[lane];
  }
  if constexpr(MODE>=1) __syncthreads();   // Wlds frag reads done before Cw overwrite

  f32x4 zero={0.f,0.f,0.f,0.f};
  float mn=1e30f,mx=-1e30f;
  float mnn[3]={1e30f,1e30f,1e30f},mxx[3]={-1e30f,-1e30f,-1e30f};
  #pragma unroll
  for(int ni=0;ni<3;ni++){
    int o=(wid*3+ni)*16+l15;
    #pragma unroll
    for(int mt=0;mt<7;mt++){
      f32x4 acc=__builtin_amdgcn_mfma_f32_16x16x32_bf16(af[mt],bfr[ni],zero,0,0,0);
      if constexpr(MODE==0){
        #pragma unroll
        for(int r=0;r<4;r++){
          mnn[ni]=fminf(mnn[ni],acc[r]); mxx[ni]=fmaxf(mxx[ni],acc[r]);
        }
      } else {
        unsigned w=0;
        #pragma unroll
        for(int r=0;r<4;r++){
          float x=fmaf(acc[r],sgi,b1s[ni]);   // quant domain, biased +128
          int iw=(int)__builtin_amdgcn_fmed3f(rintf(x),0.f,255.f);
          w|=lut_bperm(iw,lutA_w)<<(8*r);
        }
        ldsI[o*CWS+mt*4+l4]=(int)w;
      }
    }
  }
  if constexpr(MODE==0){
    #pragma unroll
    for(int ni=0;ni<3;ni++){
      mn=fminf(mn,fmaf(mnn[ni],sg,b1v[ni]));
      mx=fmaxf(mx,fmaf(mxx[ni],sg,b1v[ni]));
    }
    blkStoreMM(mn,mx,&ptmm[blockIdx.x]);
    return;
  }
  __syncthreads();

  // depthwise conv: 1536 rows (s,c), 3 per thread
  int oww[3][7];
  float mnc=1e30f,mxc=-1e30f;
  #pragma unroll
  for(int rr=0;rr<3;rr++){
    int j=t+rr*512;
    int s=j/384, c=j-s*384;
    i32x4 wq=*(const i32x4*)(wcpk+(size_t)c*16);
    float cbias=bc[c];
    float cq2=0.f;
    if constexpr(MODE==2) cq2=fmaf(cbias,inv_cv,128.f);
    int ext[11];
    ext[0]=0; ext[1]=0; ext[9]=0; ext[10]=0;
    #pragma unroll
    for(int i=0;i<7;i++) ext[2+i]=ldsI[c*CWS+s*7+i];
    int imn=0x7FFFFFFF,imx=0x80000000;
    #pragma unroll
    for(int l=0;l<LSEQ;l++){
      const int eb=l+1, bi=eb>>2, sh=eb&3;
      int A0,A1,A2,A3;
      if(sh==0){A0=ext[bi];A1=ext[bi+1];A2=ext[bi+2];A3=ext[bi+3];}
      else{
        A0=ALIGNB(ext[bi+1],ext[bi],sh);
        A1=ALIGNB(ext[bi+2],ext[bi+1],sh);
        A2=ALIGNB(ext[bi+3],ext[bi+2],sh);
        A3=ALIGNB(ext[bi+4],ext[bi+3],sh);
      }
      int idot=SDOT4(A0,wq[0],SDOT4(A1,wq[1],SDOT4(A2,wq[2],SDOT4(A3,wq[3],0))));
      if constexpr(MODE==1){
        imn=min(imn,idot); imx=max(imx,idot);
      } else {
        float x=fmaf((float)idot,ck1,cq2);
        int iw=(int)__builtin_amdgcn_fmed3f(rintf(x),0.f,255.f);
        unsigned q2=lut_bperm(iw,lutB_w);
        if((l&3)==0) oww[rr][l>>2]=(int)q2;
        else oww[rr][l>>2]|=(int)(q2<<(8*(l&3)));
      }
    }
    if constexpr(MODE==1){
      mnc=fminf(mnc,fmaf((float)imn,sfac,cbias));
      mxc=fmaxf(mxc,fmaf((float)imx,sfac,cbias));
    }
  }
  if constexpr(MODE==1){
    blkStoreMM(mnc,mxc,&ptmm[blockIdx.x]);
    return;
  }

  // MODE 2: rewrite conv codes sample-major Dw[s*DWS + c*7 + i] (10768-B stride)
  __syncthreads();
  #pragma unroll
  for(int rr=0;rr<3;rr++){
    int j=t+rr*512;
    int s=j/384, c=j-s*384;
    #pragma unroll
    for(int i=0;i<7;i++) ldsI[s*DWS+c*7+i]=oww[rr][i];
  }
  __syncthreads();

  // in-block gemm2 via i8 MFMA. K = 10752 bytes = 168 k-blocks of 64; 21 per wave.
  // A rows = samples (row clamp l15&3 keeps reads in-bounds; D rows>=4 discarded),
  // B cols = classes (cols>=10 pad, discarded).
  {
    i32x4 acc={0,0,0,0};
    const char* ldsB=(const char*)ldsI;
    for(int kb=wid;kb<168;kb+=8){
      i32x4 a=*(const i32x4*)(ldsB+(size_t)(l15&3)*(DWS*4)+kb*64+l4*16);
      i32x4 b=*(const i32x4*)(wfb+(size_t)l15*10752+kb*64+l4*16);
      acc=__builtin_amdgcn_mfma_i32_16x16x64_i8(a,b,acc,0,0,0);
    }
    if(l4==0&&l15<10){
      #pragma unroll
      for(int r=0;r<4;r++) psumN[wid][l15][r]=acc[r];
    }
  }
  __syncthreads();
  float m=0.f;
  if(t<40){
    int s=t/10, o=t-s*10;
    int sum=0;
    #pragma unroll
    for(int w=0;w<8;w++) sum+=psumN[w][o][s];
    float v=fmaf((float)sum,gsc,bfv[o]);
    lg[(blockIdx.x*4+s)*10+o]=v;
    m=fabsf(v);
  }
  if(t<64){
    #pragma unroll
    for(int off=32;off;off>>=1) m=fmaxf(m,__shfl_xor(m,off,64));
    if(t==0) ptl[blockIdx.x]=m;
  }
}

__global__ __launch_bounds__(256)
void k_final(const float* __restrict__ lg,const float* __restrict__ ptl,
             float* __restrict__ out){
  int t=threadIdx.x;
  float m=0.f;
  for(int i=t;i<1024;i+=256) m=fmaxf(m,ptl[i]);
  #pragma unroll
  for(int off=32;off;off>>=1) m=fmaxf(m,__shfl_xor(m,off,64));
  __shared__ float sm[4];
  __shared__ float sv;
  int wid=t>>6;
  if((t&63)==0) sm[wid]=m;
  __syncthreads();
  if(t==0){
    for(int k=1;k<4;k++) m=fmaxf(m,sm[k]);
    sv=fmaxf(m/127.f,1e-8f);
  }
  __syncthreads();
  float s=sv;
  int i=blockIdx.x*256+t;
  out[i]=fminf(fmaxf(rintf(lg[i]/s),-128.f),127.f)*s;
}

extern "C" void kernel_launch(void* const* d_in, const int* in_sizes, int n_in,
                              void* d_out, int out_size, void* d_ws, size_t ws_size,
                              hipStream_t stream){
  const float* img=(const float*)d_in[0];
  const float* W1 =(const float*)d_in[1];
  const float* b1 =(const float*)d_in[2];
  const float* Wc =(const float*)d_in[3];
  const float* bc =(const float*)d_in[4];
  const float* Wf =(const float*)d_in[5];
  const float* bf =(const float*)d_in[6];
  float* out=(float*)d_out;
  char* wsb=(char*)d_ws;
  float* scf=(float*)(wsb+B_SCF);
  float4* pt0=(float4*)(wsb+B_PT0);
  float2* pt1=(float2*)(wsb+B_PT1);
  float2* pt2=(float2*)(wsb+B_PT2);
  float* ptl=(float*)(wsb+B_PTL);
  float* lg=(float*)(wsb+B_LG);
  const unsigned short* xqb=(const unsigned short*)(wsb+B_XQB);
  const unsigned short* w1b=(const unsigned short*)(wsb+B_W1B);
  const char* wcpk=wsb+B_WCQ;
  const char* wfb=wsb+B_WFB;

  k_maxabs_in<<<2048,256,0,stream>>>(img,W1,Wc,Wf,pt0);
  k_red0<<<1,256,0,stream>>>(pt0,scf);
  k_prep<<<4096,256,0,stream>>>(img,W1,Wc,Wf,scf,wsb);
  k_fused<0><<<1024,512,0,stream>>>(xqb,w1b,b1,scf,nullptr,nullptr,wcpk,bc,wfb,bf,pt1,nullptr,nullptr);
  k_redmm<<<1,256,0,stream>>>(pt1,1024,scf,4,5,wsb+B_LUT1);
  k_fused<1><<<1024,512,0,stream>>>(xqb,w1b,b1,scf,wsb+B_LUT1,nullptr,wcpk,bc,wfb,bf,pt2,nullptr,nullptr);
  k_redmm<<<1,256,0,stream>>>(pt2,1024,scf,6,7,wsb+B_LUT2);
  k_fused<2><<<1024,512,0,stream>>>(xqb,w1b,b1,scf,wsb+B_LUT1,wsb+B_LUT2,wcpk,bc,wfb,bf,nullptr,lg,ptl);
  k_final<<<160,256,0,stream>>>(lg,ptl,out);
}